// Round 12
// baseline (195.426 us; speedup 1.0000x reference)
//
#include <hip/hip_runtime.h>
#include <hip/hip_bf16.h>

constexpr int B = 512, N = 64, E = 512, NE = B * E;

typedef __attribute__((ext_vector_type(8))) short bf8v;
typedef __attribute__((ext_vector_type(4))) float f32x4;
typedef __attribute__((ext_vector_type(2))) float v2f;
typedef unsigned short u16;

__device__ __forceinline__ u16 f2bf(float f) {
  unsigned u = __builtin_bit_cast(unsigned, f);
  u += 0x7FFFu + ((u >> 16) & 1u);
  return (u16)(u >> 16);
}

__device__ __forceinline__ int cmin(int a, int b) { return a < b ? a : b; }

// =================== fused 3-layer GCN: 512 threads, packed-fp32 math ===================
template <int DIN, int DOUT, int NR, int NC, bool STORE_NEXT>
__device__ __forceinline__ void gcn_layer(
    float* __restrict__ At, float* __restrict__ Xt, float* __restrict__ Hs,
    const float* __restrict__ W, const float* __restrict__ bias,
    u16* __restrict__ fout, int g, int t) {
  constexpr int XS = 68;
  constexpr int CT = DOUT / NC;
  static_assert((64 / NR) * CT == 512, "thread mapping");
  const int ct = t % CT, nt = t / CT;
  const int n0 = NR * nt, c0 = NC * ct;
  // mm1: Hs[n][c] = sum_k Xt[k][n] * W[k][c]
  if constexpr (NC == 2) {
    v2f acc[NR] = {};
#pragma unroll 8
    for (int k = 0; k < DIN; ++k) {
      float xa[NR];
      if constexpr (NR == 4) {
        float4 xv = *(const float4*)&Xt[k * XS + n0];
        xa[0] = xv.x; xa[1] = xv.y; xa[2] = xv.z; xa[3] = xv.w;
      } else {
        float2 xv = *(const float2*)&Xt[k * XS + n0];
        xa[0] = xv.x; xa[1] = xv.y;
      }
      v2f wa = __builtin_bit_cast(v2f, *(const float2*)&W[k * DOUT + c0]);
#pragma unroll
      for (int i = 0; i < NR; ++i) acc[i] += wa * xa[i];
    }
#pragma unroll
    for (int i = 0; i < NR; ++i)
      *(float2*)&Hs[(n0 + i) * XS + c0] = __builtin_bit_cast(float2, acc[i]);
  } else {
    constexpr int NP = NR / 2;
    v2f acc[NP] = {};
#pragma unroll 8
    for (int k = 0; k < DIN; ++k) {
      v2f xp[NP];
      if constexpr (NR == 4) {
        float4 xv = *(const float4*)&Xt[k * XS + n0];
        xp[0] = (v2f){xv.x, xv.y}; xp[1] = (v2f){xv.z, xv.w};
      } else {
        float2 xv = *(const float2*)&Xt[k * XS + n0];
        xp[0] = (v2f){xv.x, xv.y};
      }
      float wa = W[k * DOUT + c0];
#pragma unroll
      for (int p = 0; p < NP; ++p) acc[p] += xp[p] * wa;
    }
#pragma unroll
    for (int p = 0; p < NP; ++p) {
      Hs[(n0 + 2 * p + 0) * XS + c0] = acc[p][0];
      Hs[(n0 + 2 * p + 1) * XS + c0] = acc[p][1];
    }
  }
  __syncthreads();
  // mm2: out[d][c] = sum_s At[s][d] * Hs[s][c] + bias[c]
  if constexpr (NC == 2) {
    v2f acc[NR] = {};
#pragma unroll 8
    for (int s = 0; s < N; ++s) {
      float aa[NR];
      if constexpr (NR == 4) {
        float4 av = *(const float4*)&At[s * XS + n0];
        aa[0] = av.x; aa[1] = av.y; aa[2] = av.z; aa[3] = av.w;
      } else {
        float2 av = *(const float2*)&At[s * XS + n0];
        aa[0] = av.x; aa[1] = av.y;
      }
      v2f hv = __builtin_bit_cast(v2f, *(const float2*)&Hs[s * XS + c0]);
#pragma unroll
      for (int i = 0; i < NR; ++i) acc[i] += hv * aa[i];
    }
    const v2f bv = __builtin_bit_cast(v2f, *(const float2*)&bias[c0]);
#pragma unroll
    for (int i = 0; i < NR; ++i) {
      v2f st = acc[i] + bv;
      unsigned pack = (unsigned)f2bf(st[0]) | ((unsigned)f2bf(st[1]) << 16);
      *(unsigned*)&fout[(size_t)g * N * DOUT + (size_t)(n0 + i) * DOUT + c0] = pack;
      if (STORE_NEXT) {
        Xt[(c0 + 0) * XS + n0 + i] = fmaxf(st[0], 0.f);
        Xt[(c0 + 1) * XS + n0 + i] = fmaxf(st[1], 0.f);
      }
    }
  } else {
    constexpr int NP = NR / 2;
    v2f acc[NP] = {};
#pragma unroll 8
    for (int s = 0; s < N; ++s) {
      v2f ap[NP];
      if constexpr (NR == 4) {
        float4 av = *(const float4*)&At[s * XS + n0];
        ap[0] = (v2f){av.x, av.y}; ap[1] = (v2f){av.z, av.w};
      } else {
        float2 av = *(const float2*)&At[s * XS + n0];
        ap[0] = (v2f){av.x, av.y};
      }
      float ha = Hs[s * XS + c0];
#pragma unroll
      for (int p = 0; p < NP; ++p) acc[p] += ap[p] * ha;
    }
    const float bv0 = bias[c0];
#pragma unroll
    for (int p = 0; p < NP; ++p)
#pragma unroll
      for (int e = 0; e < 2; ++e) {
        float stv = acc[p][e] + bv0;
        fout[(size_t)g * N * DOUT + (size_t)(n0 + 2 * p + e) * DOUT + c0] = f2bf(stv);
        if (STORE_NEXT) Xt[c0 * XS + n0 + 2 * p + e] = fmaxf(stv, 0.f);
      }
  }
  __syncthreads();
}

__global__ __launch_bounds__(512) void gcn_fused(
    const float* __restrict__ xq, const float* __restrict__ xc,
    const float* __restrict__ W1, const float* __restrict__ b1,
    const float* __restrict__ W2, const float* __restrict__ b2,
    const float* __restrict__ W3, const float* __restrict__ b3,
    const int* __restrict__ eq, const int* __restrict__ ec,
    u16* __restrict__ f1q, u16* __restrict__ f1c,
    u16* __restrict__ f2q, u16* __restrict__ f2c,
    u16* __restrict__ f3q, u16* __restrict__ f3c) {
  constexpr int XS = 68;
  __shared__ __align__(16) float At[N * XS];
  __shared__ __align__(16) float Xt[N * XS];
  __shared__ __align__(16) float Hs[N * XS];
  __shared__ float dl[N];
  __shared__ int cnt[N];
  const int g = blockIdx.x, t = threadIdx.x;
  const float* x = blockIdx.y ? xc : xq;
  const int* edges = blockIdx.y ? ec : eq;
  u16* o1 = blockIdx.y ? f1c : f1q;
  u16* o2 = blockIdx.y ? f2c : f2q;
  u16* o3 = blockIdx.y ? f3c : f3q;
  for (int i = t; i < N * 16; i += 512) {
    int n = i / 16, k = i % 16;
    Xt[k * XS + n] = x[(size_t)g * N * 16 + i];
  }
  for (int i = t; i < N * XS; i += 512) At[i] = 0.f;
  if (t < N) cnt[t] = 1;
  __syncthreads();
  const int* srcp = edges + (size_t)g * E;
  const int* dstp = edges + NE + (size_t)g * E;
  for (int j = t; j < E; j += 512) atomicAdd(&cnt[dstp[j] & 63], 1);
  __syncthreads();
  if (t < N) dl[t] = rsqrtf((float)cnt[t]);
  __syncthreads();
  for (int j = t; j < E; j += 512) {
    int s = srcp[j] & 63, d = dstp[j] & 63;
    atomicAdd(&At[s * XS + d], dl[s] * dl[d]);
  }
  if (t < N) atomicAdd(&At[t * XS + t], dl[t] * dl[t]);
  __syncthreads();
  gcn_layer<16, 64, 4, 2, true>(At, Xt, Hs, W1, b1, o1, g, t);
  gcn_layer<64, 32, 4, 1, true>(At, Xt, Hs, W2, b2, o2, g, t);
  gcn_layer<32, 16, 2, 1, false>(At, Xt, Hs, W3, b3, o3, g, t);
}

// =================== fused sim (bf16 MFMA) + conv1 (packed fp32, oc-pairs) ===================
__global__ __launch_bounds__(256, 4) void simconv1(
    const u16* __restrict__ f1q, const u16* __restrict__ f1c,
    const u16* __restrict__ f2q, const u16* __restrict__ f2c,
    const u16* __restrict__ f3q, const u16* __restrict__ f3c,
    const float* __restrict__ w, const float* __restrict__ bias,
    u16* __restrict__ out) {
  constexpr int PS = 68, QS = 72;
  __shared__ __align__(16) u16 Qs[64 * QS];
  __shared__ __align__(16) u16 Cs[64 * QS];
  __shared__ __align__(16) float simp[68 * 68];
  __shared__ float wls[25 * 8];  // [tap][oc]
  __shared__ float bls[8];
  const int b = blockIdx.x, m = blockIdx.y, t = threadIdx.x;
  for (int i = t; i < 68 * 68; i += 256) simp[i] = 0.f;
  if (t < 200) {
    int oc = t / 25, tap = t % 25;
    wls[tap * 8 + oc] = w[m * 200 + t];
  }
  if (t < 8) bls[t] = bias[m * 8 + t];
  const u16* fq = (m == 0) ? f1q : (m == 1) ? f2q : f3q;
  const u16* fc = (m == 0) ? f1c : (m == 1) ? f2c : f3c;
  const int D = 64 >> m;
  const int SEG = D >> 3;
  for (int i = t; i < 64 * SEG; i += 256) {
    int n = i / SEG, s = i - n * SEG;
    *(uint4*)&Qs[n * QS + s * 8] = *(const uint4*)&fq[(size_t)b * 64 * D + n * D + s * 8];
    *(uint4*)&Cs[n * QS + s * 8] = *(const uint4*)&fc[(size_t)b * 64 * D + n * D + s * 8];
  }
  if (m == 2 && t < 128) {
    int n = t >> 1, s = t & 1;
    uint4 z = {0u, 0u, 0u, 0u};
    *(uint4*)&Qs[n * QS + 16 + s * 8] = z;
    *(uint4*)&Cs[n * QS + 16 + s * 8] = z;
  }
  __syncthreads();
  const int w4 = t >> 6, lane = t & 63;
  const int r16 = lane & 15, kg = lane >> 4;
  const int Kpad = (m == 0) ? 64 : 32;
#pragma unroll 1
  for (int ct = 0; ct < 4; ++ct) {
    f32x4 acc = {0.f, 0.f, 0.f, 0.f};
    for (int ks = 0; ks < Kpad; ks += 32) {
      bf8v a = *(const bf8v*)&Qs[(w4 * 16 + r16) * QS + ks + kg * 8];
      bf8v bb = *(const bf8v*)&Cs[(ct * 16 + r16) * QS + ks + kg * 8];
      acc = __builtin_amdgcn_mfma_f32_16x16x32_bf16(a, bb, acc, 0, 0, 0);
    }
#pragma unroll
    for (int j = 0; j < 4; ++j)
      simp[(w4 * 16 + kg * 4 + j + 2) * PS + ct * 16 + r16 + 2] = acc[j];
  }
  __syncthreads();
  const int gy = t >> 4, gx = t & 15;
  float pr[8][8];
#pragma unroll
  for (int yy = 0; yy < 8; ++yy) {
    float4 a = *(const float4*)&simp[(4 * gy + yy) * PS + 4 * gx];
    float4 bb = *(const float4*)&simp[(4 * gy + yy) * PS + 4 * gx + 4];
    pr[yy][0] = a.x; pr[yy][1] = a.y; pr[yy][2] = a.z; pr[yy][3] = a.w;
    pr[yy][4] = bb.x; pr[yy][5] = bb.y; pr[yy][6] = bb.z; pr[yy][7] = bb.w;
  }
  u16* op = out + (size_t)(b * 3 + m) * 8192;
#pragma unroll 1
  for (int p2 = 0; p2 < 4; ++p2) {
    v2f accp[16];
#pragma unroll
    for (int p = 0; p < 16; ++p) accp[p] = (v2f){0.f, 0.f};
#pragma unroll
    for (int ky = 0; ky < 5; ++ky)
#pragma unroll
      for (int kx = 0; kx < 5; ++kx) {
        v2f wv = __builtin_bit_cast(v2f, *(const float2*)&wls[(ky * 5 + kx) * 8 + p2 * 2]);
#pragma unroll
        for (int dy = 0; dy < 4; ++dy)
#pragma unroll
          for (int dx = 0; dx < 4; ++dx)
            accp[dy * 4 + dx] += wv * pr[ky + dy][kx + dx];
      }
    const float b0 = bls[p2 * 2], b1 = bls[p2 * 2 + 1];
#pragma unroll
    for (int ay = 0; ay < 2; ++ay)
#pragma unroll
      for (int ax = 0; ax < 2; ++ax) {
        float v0 = fmaxf(fmaxf(accp[(2 * ay) * 4 + 2 * ax][0], accp[(2 * ay) * 4 + 2 * ax + 1][0]),
                         fmaxf(accp[(2 * ay + 1) * 4 + 2 * ax][0], accp[(2 * ay + 1) * 4 + 2 * ax + 1][0]));
        float v1 = fmaxf(fmaxf(accp[(2 * ay) * 4 + 2 * ax][1], accp[(2 * ay) * 4 + 2 * ax + 1][1]),
                         fmaxf(accp[(2 * ay + 1) * 4 + 2 * ax][1], accp[(2 * ay + 1) * 4 + 2 * ax + 1][1]));
        v0 = fmaxf(v0 + b0, 0.f);
        v1 = fmaxf(v1 + b1, 0.f);
        unsigned pack = (unsigned)f2bf(v0) | ((unsigned)f2bf(v1) << 16);
        *(unsigned*)&op[(size_t)(((2 * gy + ay) * 32) + (2 * gx + ax)) * 8 + p2 * 2] = pack;
      }
  }
}

// =================== prep: wcvt (blocks 0..383) + wprep (blocks 384..579) ===================
__global__ __launch_bounds__(256) void prep_kernel(
    const float* __restrict__ lw1, const float* __restrict__ cw2,
    const float* __restrict__ cw3, u16* __restrict__ wT,
    u16* __restrict__ w2p, u16* __restrict__ w3p) {
  const int t = threadIdx.x;
  if (blockIdx.x < 384) {
    __shared__ float tile[64][65];
    const int k0 = (blockIdx.x % 96) * 64, c0 = (blockIdx.x / 96) * 64;
    for (int i = t; i < 4096; i += 256) {
      int r = i >> 6, c = i & 63;
      tile[r][c] = lw1[(size_t)(k0 + r) * 256 + c0 + c];
    }
    __syncthreads();
    for (int i = t; i < 4096; i += 256) {
      int c = i >> 6, k = i & 63;
      wT[(size_t)(c0 + c) * 6144 + k0 + k] = f2bf(tile[k][c]);
    }
    return;
  }
  int i = (blockIdx.x - 384) * 256 + t;
  if (i < 3 * 7 * 16 * 40) {
    int m = i / 4480, r = i % 4480;
    int k = r % 40, rest = r / 40, oc = rest & 15, st = rest >> 4;
    u16 v = 0;
    if (k < 32) {
      int sl = k >> 3, ci = k & 7, tap = st * 4 + sl;
      if (tap < 25) v = f2bf(cw2[((size_t)(m * 16 + oc) * 8 + ci) * 25 + tap]);
    }
    w2p[i] = v;
  }
  if (i < 3 * 26 * 16 * 40) {
    int m = i / 16640, r = i % 16640;
    int k = r % 40, rest = r / 40, oc16 = rest & 15, sthalf = rest >> 4;
    int half = sthalf & 1, st = sthalf >> 1;
    u16 v = 0;
    if (k < 32) {
      int sl = k >> 4, ci = k & 15, tap = st * 2 + sl;
      int oc = half * 16 + oc16;
      if (tap < 25) v = f2bf(cw3[((size_t)(m * 32 + oc) * 16 + ci) * 25 + tap]);
    }
    w3p[i] = v;
  }
}

// =================== conv2: bf16 MFMA, weight-hoisted, div-free (unchanged) ===================
__global__ __launch_bounds__(256) void conv2_mfma(
    const u16* __restrict__ in, const u16* __restrict__ w2p,
    const float* __restrict__ bias, u16* __restrict__ out) {
  constexpr int PW = 36, BS = 40;
  __shared__ __align__(16) u16 ins[PW * PW * 8];
  __shared__ __align__(16) u16 wls[7 * 16 * BS];
  __shared__ float bls[16];
  const int b = blockIdx.x, m = blockIdx.y, t = threadIdx.x;
  const size_t ibase = (size_t)(b * 3 + m) * 8192;
  for (int i = t; i < PW * PW; i += 256) {
    int y = i / PW, x = i % PW;
    uint4 v = {0u, 0u, 0u, 0u};
    if (y >= 2 && y < 34 && x >= 2 && x < 34)
      v = *(const uint4*)&in[ibase + (size_t)((y - 2) * 32 + (x - 2)) * 8];
    *(uint4*)&ins[i * 8] = v;
  }
  {
    const u16* wsrc = w2p + m * 4480;
    for (int i = t; i < 560; i += 256) *(uint4*)&wls[i * 8] = *(const uint4*)&wsrc[i * 8];
  }
  if (t < 16) bls[t] = bias[m * 16 + t];
  __syncthreads();
  const int wv = t >> 6, lane = t & 63;
  const int oc = lane & 15, g = lane >> 4;
  const int xt = wv & 1, ypb = wv >> 1;
  const int x = xt * 16 + oc;
  const size_t obase = (size_t)(b * 3 + m) * 4096;
#pragma unroll 1
  for (int grp = 0; grp < 2; ++grp) {
    f32x4 acc[4][2];
#pragma unroll
    for (int i = 0; i < 4; ++i) {
      acc[i][0] = (f32x4){0.f, 0.f, 0.f, 0.f};
      acc[i][1] = (f32x4){0.f, 0.f, 0.f, 0.f};
    }
#pragma unroll
    for (int st = 0; st < 7; ++st) {
      bf8v bvv = *(const bf8v*)&wls[(st * 16 + oc) * BS + g * 8];
      const int c0 = cmin(st * 4 + 0, 24), c1 = cmin(st * 4 + 1, 24);
      const int c2 = cmin(st * 4 + 2, 24), c3 = cmin(st * 4 + 3, 24);
      const int k0 = (c0 / 5) * PW + c0 % 5, k1 = (c1 / 5) * PW + c1 % 5;
      const int k2 = (c2 / 5) * PW + c2 % 5, k3 = (c3 / 5) * PW + c3 % 5;
      const int koff = (g == 0) ? k0 : (g == 1) ? k1 : (g == 2) ? k2 : k3;
#pragma unroll
      for (int i = 0; i < 4; ++i) {
        const int y0 = 2 * ypb + 4 * (grp * 4 + i);
        const int abase = (y0 * PW + x + koff) * 8;
        bf8v a0 = *(const bf8v*)&ins[abase];
        acc[i][0] = __builtin_amdgcn_mfma_f32_16x16x32_bf16(a0, bvv, acc[i][0], 0, 0, 0);
        bf8v a1 = *(const bf8v*)&ins[abase + PW * 8];
        acc[i][1] = __builtin_amdgcn_mfma_f32_16x16x32_bf16(a1, bvv, acc[i][1], 0, 0, 0);
      }
    }
    const float bb = bls[oc];
#pragma unroll
    for (int i = 0; i < 4; ++i) {
      const int yp = ypb + 2 * (grp * 4 + i);
      const float v0 = fmaxf(fmaxf(fmaxf(acc[i][0][0], acc[i][0][1]),
                                   fmaxf(acc[i][1][0], acc[i][1][1])) + bb, 0.f);
      const float v1 = fmaxf(fmaxf(fmaxf(acc[i][0][2], acc[i][0][3]),
                                   fmaxf(acc[i][1][2], acc[i][1][3])) + bb, 0.f);
      const int px = xt * 8 + 2 * g;
      out[obase + (size_t)((yp * 16 + px) * 16 + oc)] = f2bf(v0);
      out[obase + (size_t)((yp * 16 + px + 1) * 16 + oc)] = f2bf(v1);
    }
  }
}

// =================== conv3: bf16 MFMA, weight-hoisted, div-free (unchanged) ===================
__global__ __launch_bounds__(256) void conv3_mfma(
    const u16* __restrict__ in, const u16* __restrict__ w3p,
    const float* __restrict__ bias, u16* __restrict__ feat) {
  constexpr int PW = 20, BS = 40;
  __shared__ __align__(16) u16 ins[PW * PW * 16];
  __shared__ __align__(16) u16 wls[26 * 16 * BS];
  __shared__ float bls[32];
  const int b = blockIdx.x, m = blockIdx.y, t = threadIdx.x;
  const size_t ibase = (size_t)(b * 3 + m) * 4096;
  for (int i = t; i < PW * PW; i += 256) {
    int y = i / PW, x = i % PW;
    uint4 v0 = {0u, 0u, 0u, 0u}, v1 = {0u, 0u, 0u, 0u};
    if (y >= 2 && y < 18 && x >= 2 && x < 18) {
      const u16* p = &in[ibase + (size_t)((y - 2) * 16 + (x - 2)) * 16];
      v0 = *(const uint4*)p;
      v1 = *(const uint4*)(p + 8);
    }
    *(uint4*)&ins[i * 16] = v0;
    *(uint4*)&ins[i * 16 + 8] = v1;
  }
  {
    const u16* wsrc = w3p + m * 16640;
    for (int i = t; i < 2080; i += 256) *(uint4*)&wls[i * 8] = *(const uint4*)&wsrc[i * 8];
  }
  if (t < 32) bls[t] = bias[m * 32 + t];
  __syncthreads();
  const int wv = t >> 6, lane = t & 63;
  const int oc = lane & 15, g = lane >> 4;
  const int sl = g >> 1, ch = (g & 1) * 8;
  const int half = wv & 1, ypb = wv >> 1;
  u16* fb = feat + (size_t)b * 6144 + m * 2048;
  f32x4 acc[4][2];
#pragma unroll
  for (int i = 0; i < 4; ++i) {
    acc[i][0] = (f32x4){0.f, 0.f, 0.f, 0.f};
    acc[i][1] = (f32x4){0.f, 0.f, 0.f, 0.f};
  }
#pragma unroll
  for (int st = 0; st < 13; ++st) {
    bf8v bvv = *(const bf8v*)&wls[(size_t)((st * 2 + half) * 16 + oc) * BS + g * 8];
    const int c0 = cmin(st * 2 + 0, 24), c1 = cmin(st * 2 + 1, 24);
    const int k0 = (c0 / 5) * PW + c0 % 5, k1 = (c1 / 5) * PW + c1 % 5;
    const int koff = sl ? k1 : k0;
#pragma unroll
    for (int i = 0; i < 4; ++i) {
      const int y0 = 2 * ypb + 4 * i;
      const int abase = (y0 * PW + oc + koff) * 16 + ch;
      bf8v a0 = *(const bf8v*)&ins[abase];
      acc[i][0] = __builtin_amdgcn_mfma_f32_16x16x32_bf16(a0, bvv, acc[i][0], 0, 0, 0);
      bf8v a1 = *(const bf8v*)&ins[abase + PW * 16];
      acc[i][1] = __builtin_amdgcn_mfma_f32_16x16x32_bf16(a1, bvv, acc[i][1], 0, 0, 0);
    }
  }
  const int ocg = half * 16 + oc;
  const float bb = bls[ocg];
#pragma unroll
  for (int i = 0; i < 4; ++i) {
    const int yp = ypb + 2 * i;
    const float v0 = fmaxf(fmaxf(fmaxf(acc[i][0][0], acc[i][0][1]),
                                 fmaxf(acc[i][1][0], acc[i][1][1])) + bb, 0.f);
    const float v1 = fmaxf(fmaxf(fmaxf(acc[i][0][2], acc[i][0][3]),
                                 fmaxf(acc[i][1][2], acc[i][1][3])) + bb, 0.f);
    unsigned pack = (unsigned)f2bf(v0) | ((unsigned)f2bf(v1) << 16);
    *(unsigned*)&fb[ocg * 64 + yp * 8 + 2 * g] = pack;
  }
}

// =================== lin1: bf16 MFMA GEMM (unchanged) ===================
__global__ __launch_bounds__(256) void lin1_mfma(const u16* __restrict__ feat,
                                                 const u16* __restrict__ wT,
                                                 float* __restrict__ h1p) {
  constexpr int AS = 72;
  __shared__ __align__(16) u16 As[64 * AS];
  __shared__ __align__(16) u16 Bs[64 * AS];
  const int r0 = blockIdx.x * 64, c0 = blockIdx.y * 64, kb = blockIdx.z * 384;
  const int t = threadIdx.x;
  const int w = t >> 6, lane = t & 63;
  const int row16 = lane & 15, kg = lane >> 4;
  f32x4 acc[4] = {{0.f, 0.f, 0.f, 0.f}, {0.f, 0.f, 0.f, 0.f},
                  {0.f, 0.f, 0.f, 0.f}, {0.f, 0.f, 0.f, 0.f}};
  const int lr = t >> 2, lk = (t & 3) * 16;
#pragma unroll 1
  for (int st = 0; st < 6; ++st) {
    __syncthreads();
    const int ks = kb + st * 64;
    {
      const u16* srcA = feat + (size_t)(r0 + lr) * 6144 + ks + lk;
      uint4 a0 = *(const uint4*)srcA;
      uint4 a1 = *(const uint4*)(srcA + 8);
      *(uint4*)&As[lr * AS + lk] = a0;
      *(uint4*)&As[lr * AS + lk + 8] = a1;
      const u16* srcB = wT + (size_t)(c0 + lr) * 6144 + ks + lk;
      uint4 b0 = *(const uint4*)srcB;
      uint4 b1 = *(const uint4*)(srcB + 8);
      *(uint4*)&Bs[lr * AS + lk] = b0;
      *(uint4*)&Bs[lr * AS + lk + 8] = b1;
    }
    __syncthreads();
#pragma unroll
    for (int kk = 0; kk < 2; ++kk) {
      bf8v a = *(const bf8v*)&As[(w * 16 + row16) * AS + kk * 32 + kg * 8];
#pragma unroll
      for (int ct = 0; ct < 4; ++ct) {
        bf8v bb = *(const bf8v*)&Bs[(ct * 16 + row16) * AS + kk * 32 + kg * 8];
        acc[ct] = __builtin_amdgcn_mfma_f32_16x16x32_bf16(a, bb, acc[ct], 0, 0, 0);
      }
    }
  }
  float* out = h1p + (size_t)blockIdx.z * 131072;
#pragma unroll
  for (int ct = 0; ct < 4; ++ct)
#pragma unroll
    for (int j = 0; j < 4; ++j)
      out[(size_t)(r0 + w * 16 + kg * 4 + j) * 256 + c0 + ct * 16 + row16] = acc[ct][j];
}

// =================== head (unchanged) ===================
__global__ __launch_bounds__(256) void head_kernel(
    const float* __restrict__ h1p, const float* __restrict__ b1,
    const float* __restrict__ w2, const float* __restrict__ b2,
    const float* __restrict__ sw, const float* __restrict__ sb,
    float* __restrict__ out) {
  constexpr int HS = 260;
  __shared__ __align__(16) float h1s[16 * HS];
  __shared__ __align__(16) float w2s[256 * 16];
  const int r0 = blockIdx.x * 16, t = threadIdx.x;
  for (int i = t; i < 4096; i += 256) {
    int r = i >> 8, k = i & 255;
    float s = b1[k];
#pragma unroll
    for (int p = 0; p < 16; ++p) s += h1p[(size_t)p * 131072 + (size_t)(r0 + r) * 256 + k];
    h1s[r * HS + k] = s;
    w2s[i] = w2[i];
  }
  __syncthreads();
  const int j = t & 15, r = t >> 4;
  float acc = b2[j];
#pragma unroll 4
  for (int k4 = 0; k4 < 64; ++k4) {
    float4 hv = *(const float4*)&h1s[r * HS + 4 * k4];
    float h0 = fmaxf(hv.x, 0.f), h1v = fmaxf(hv.y, 0.f);
    float h2v = fmaxf(hv.z, 0.f), h3 = fmaxf(hv.w, 0.f);
    acc += h0 * w2s[(4 * k4 + 0) * 16 + j];
    acc += h1v * w2s[(4 * k4 + 1) * 16 + j];
    acc += h2v * w2s[(4 * k4 + 2) * 16 + j];
    acc += h3 * w2s[(4 * k4 + 3) * 16 + j];
  }
  float v = fmaxf(acc, 0.f) * sw[j];
#pragma unroll
  for (int off = 8; off; off >>= 1) v += __shfl_xor(v, off, 16);
  if (j == 0) out[r0 + r] = v + sb[0];
}

// =================== launcher ===================
extern "C" void kernel_launch(void* const* d_in, const int* in_sizes, int n_in,
                              void* d_out, int out_size, void* d_ws, size_t ws_size,
                              hipStream_t stream) {
  const float* x_q = (const float*)d_in[0];
  const float* x_c = (const float*)d_in[1];
  const int* edge_q = (const int*)d_in[2];
  const int* edge_c = (const int*)d_in[3];
  const float* gw1 = (const float*)d_in[4];
  const float* gb1 = (const float*)d_in[5];
  const float* gw2 = (const float*)d_in[6];
  const float* gb2 = (const float*)d_in[7];
  const float* gw3 = (const float*)d_in[8];
  const float* gb3 = (const float*)d_in[9];
  const float* cw1 = (const float*)d_in[10];
  const float* cb1 = (const float*)d_in[11];
  const float* cw2 = (const float*)d_in[12];
  const float* cb2 = (const float*)d_in[13];
  const float* cw3 = (const float*)d_in[14];
  const float* cb3 = (const float*)d_in[15];
  const float* lw1 = (const float*)d_in[16];
  const float* lb1 = (const float*)d_in[17];
  const float* lw2 = (const float*)d_in[18];
  const float* lb2 = (const float*)d_in[19];
  const float* swt = (const float*)d_in[20];
  const float* sbs = (const float*)d_in[21];
  float* ws = (float*)d_ws;

  const size_t o_f1q = 65536;
  const size_t o_f2q = o_f1q + 2097152;
  const size_t o_f3q = o_f2q + 1048576;
  const size_t o_f1c = o_f3q + 524288;
  const size_t o_f2c = o_f1c + 2097152;
  const size_t o_f3c = o_f2c + 1048576;
  const size_t o_sims = o_f3c + 524288;
  const size_t o_pm1 = o_sims + 6291456;
  const size_t o_pm2 = o_pm1 + 6291456;
  const size_t o_wT = o_pm2 + 3145728;
  const size_t o_w2p = o_wT + 786432;
  const size_t o_w3p = o_w2p + 8192;
  const size_t o_feat = o_sims;           // bf16 feat
  const size_t o_h1p = o_f1q;             // reuse (f1q dead after simconv1)

  u16* f1q = (u16*)(ws + o_f1q); u16* f2q = (u16*)(ws + o_f2q); u16* f3q = (u16*)(ws + o_f3q);
  u16* f1c = (u16*)(ws + o_f1c); u16* f2c = (u16*)(ws + o_f2c); u16* f3c = (u16*)(ws + o_f3c);
  u16* pm1 = (u16*)(ws + o_pm1);
  u16* pm2 = (u16*)(ws + o_pm2);
  u16* wT = (u16*)(ws + o_wT);
  u16* w2p = (u16*)(ws + o_w2p);
  u16* w3p = (u16*)(ws + o_w3p);
  u16* feat = (u16*)(ws + o_feat);
  float* h1p = ws + o_h1p;

  prep_kernel<<<580, 256, 0, stream>>>(lw1, cw2, cw3, wT, w2p, w3p);

  gcn_fused<<<dim3(B, 2), 512, 0, stream>>>(x_q, x_c, gw1, gb1, gw2, gb2, gw3, gb3,
                                            edge_q, edge_c, f1q, f1c, f2q, f2c, f3q, f3c);

  simconv1<<<dim3(B, 3), 256, 0, stream>>>(f1q, f1c, f2q, f2c, f3q, f3c, cw1, cb1, pm1);

  conv2_mfma<<<dim3(B, 3), 256, 0, stream>>>(pm1, w2p, cb2, pm2);
  conv3_mfma<<<dim3(B, 3), 256, 0, stream>>>(pm2, w3p, cb3, feat);

  lin1_mfma<<<dim3(8, 4, 16), 256, 0, stream>>>(feat, wT, h1p);
  head_kernel<<<32, 256, 0, stream>>>(h1p, lb1, lw2, lb2, swt, sbs, (float*)d_out);
}

// Round 13
// 131.085 us; speedup vs baseline: 1.4908x; 1.4908x over previous
//
#include <hip/hip_runtime.h>
#include <hip/hip_bf16.h>

constexpr int B = 512, N = 64, E = 512, NE = B * E;

typedef __attribute__((ext_vector_type(8))) short bf8v;
typedef __attribute__((ext_vector_type(4))) float f32x4;
typedef unsigned short u16;

__device__ __forceinline__ u16 f2bf(float f) {
  unsigned u = __builtin_bit_cast(unsigned, f);
  u += 0x7FFFu + ((u >> 16) & 1u);
  return (u16)(u >> 16);
}

__device__ __forceinline__ int cmin(int a, int b) { return a < b ? a : b; }

// =================== fused 3-layer GCN: 512 threads, all-thread layers (round-11 state) ===================
template <int DIN, int DOUT, int NR, int NC, bool STORE_NEXT>
__device__ __forceinline__ void gcn_layer(
    float* __restrict__ At, float* __restrict__ Xt, float* __restrict__ Hs,
    const float* __restrict__ W, const float* __restrict__ bias,
    u16* __restrict__ fout, int g, int t) {
  constexpr int XS = 68;
  constexpr int CT = DOUT / NC;
  static_assert((64 / NR) * CT == 512, "thread mapping");
  const int ct = t % CT, nt = t / CT;
  const int n0 = NR * nt, c0 = NC * ct;
  {
    float acc[NR][NC] = {};
#pragma unroll 4
    for (int k = 0; k < DIN; ++k) {
      float xa[NR];
      if constexpr (NR == 4) {
        float4 xv = *(const float4*)&Xt[k * XS + n0];
        xa[0] = xv.x; xa[1] = xv.y; xa[2] = xv.z; xa[3] = xv.w;
      } else {
        float2 xv = *(const float2*)&Xt[k * XS + n0];
        xa[0] = xv.x; xa[1] = xv.y;
      }
      float wa[NC];
      if constexpr (NC == 2) {
        float2 wv = *(const float2*)&W[k * DOUT + c0];
        wa[0] = wv.x; wa[1] = wv.y;
      } else {
        wa[0] = W[k * DOUT + c0];
      }
#pragma unroll
      for (int i = 0; i < NR; ++i)
#pragma unroll
        for (int j = 0; j < NC; ++j) acc[i][j] += xa[i] * wa[j];
    }
#pragma unroll
    for (int i = 0; i < NR; ++i) {
      if constexpr (NC == 2)
        *(float2*)&Hs[(n0 + i) * XS + c0] = make_float2(acc[i][0], acc[i][1]);
      else
        Hs[(n0 + i) * XS + c0] = acc[i][0];
    }
  }
  __syncthreads();
  {
    float acc[NR][NC] = {};
#pragma unroll 4
    for (int s = 0; s < N; ++s) {
      float aa[NR];
      if constexpr (NR == 4) {
        float4 av = *(const float4*)&At[s * XS + n0];
        aa[0] = av.x; aa[1] = av.y; aa[2] = av.z; aa[3] = av.w;
      } else {
        float2 av = *(const float2*)&At[s * XS + n0];
        aa[0] = av.x; aa[1] = av.y;
      }
      float ha[NC];
      if constexpr (NC == 2) {
        float2 hv = *(const float2*)&Hs[s * XS + c0];
        ha[0] = hv.x; ha[1] = hv.y;
      } else {
        ha[0] = Hs[s * XS + c0];
      }
#pragma unroll
      for (int i = 0; i < NR; ++i)
#pragma unroll
        for (int j = 0; j < NC; ++j) acc[i][j] += aa[i] * ha[j];
    }
    float bv[NC];
#pragma unroll
    for (int j = 0; j < NC; ++j) bv[j] = bias[c0 + j];
#pragma unroll
    for (int i = 0; i < NR; ++i) {
      float st[NC];
#pragma unroll
      for (int j = 0; j < NC; ++j) st[j] = acc[i][j] + bv[j];
      if constexpr (NC == 2) {
        unsigned pack = (unsigned)f2bf(st[0]) | ((unsigned)f2bf(st[1]) << 16);
        *(unsigned*)&fout[(size_t)g * N * DOUT + (size_t)(n0 + i) * DOUT + c0] = pack;
      } else {
        fout[(size_t)g * N * DOUT + (size_t)(n0 + i) * DOUT + c0] = f2bf(st[0]);
      }
      if (STORE_NEXT) {
#pragma unroll
        for (int j = 0; j < NC; ++j)
          Xt[(c0 + j) * XS + n0 + i] = fmaxf(st[j], 0.f);
      }
    }
  }
  __syncthreads();
}

__global__ __launch_bounds__(512) void gcn_fused(
    const float* __restrict__ xq, const float* __restrict__ xc,
    const float* __restrict__ W1, const float* __restrict__ b1,
    const float* __restrict__ W2, const float* __restrict__ b2,
    const float* __restrict__ W3, const float* __restrict__ b3,
    const int* __restrict__ eq, const int* __restrict__ ec,
    u16* __restrict__ f1q, u16* __restrict__ f1c,
    u16* __restrict__ f2q, u16* __restrict__ f2c,
    u16* __restrict__ f3q, u16* __restrict__ f3c) {
  constexpr int XS = 68;
  __shared__ __align__(16) float At[N * XS];
  __shared__ __align__(16) float Xt[N * XS];
  __shared__ __align__(16) float Hs[N * XS];
  __shared__ float dl[N];
  __shared__ int cnt[N];
  const int g = blockIdx.x, t = threadIdx.x;
  const float* x = blockIdx.y ? xc : xq;
  const int* edges = blockIdx.y ? ec : eq;
  u16* o1 = blockIdx.y ? f1c : f1q;
  u16* o2 = blockIdx.y ? f2c : f2q;
  u16* o3 = blockIdx.y ? f3c : f3q;
  for (int i = t; i < N * 16; i += 512) {
    int n = i / 16, k = i % 16;
    Xt[k * XS + n] = x[(size_t)g * N * 16 + i];
  }
  for (int i = t; i < N * XS; i += 512) At[i] = 0.f;
  if (t < N) cnt[t] = 1;
  __syncthreads();
  const int* srcp = edges + (size_t)g * E;
  const int* dstp = edges + NE + (size_t)g * E;
  for (int j = t; j < E; j += 512) atomicAdd(&cnt[dstp[j] & 63], 1);
  __syncthreads();
  if (t < N) dl[t] = rsqrtf((float)cnt[t]);
  __syncthreads();
  for (int j = t; j < E; j += 512) {
    int s = srcp[j] & 63, d = dstp[j] & 63;
    atomicAdd(&At[s * XS + d], dl[s] * dl[d]);
  }
  if (t < N) atomicAdd(&At[t * XS + t], dl[t] * dl[t]);
  __syncthreads();
  gcn_layer<16, 64, 4, 2, true>(At, Xt, Hs, W1, b1, o1, g, t);
  gcn_layer<64, 32, 4, 1, true>(At, Xt, Hs, W2, b2, o2, g, t);
  gcn_layer<32, 16, 2, 1, false>(At, Xt, Hs, W3, b3, o3, g, t);
}

// =================== fused sim (bf16 MFMA) + conv1 (fp32 VALU, oc-pairs) — round-11 state ===================
__global__ __launch_bounds__(256, 4) void simconv1(
    const u16* __restrict__ f1q, const u16* __restrict__ f1c,
    const u16* __restrict__ f2q, const u16* __restrict__ f2c,
    const u16* __restrict__ f3q, const u16* __restrict__ f3c,
    const float* __restrict__ w, const float* __restrict__ bias,
    u16* __restrict__ out) {
  constexpr int PS = 68, QS = 72;
  __shared__ __align__(16) u16 Qs[64 * QS];
  __shared__ __align__(16) u16 Cs[64 * QS];
  __shared__ __align__(16) float simp[68 * 68];
  __shared__ float wls[25 * 8];  // [tap][oc]
  __shared__ float bls[8];
  const int b = blockIdx.x, m = blockIdx.y, t = threadIdx.x;
  for (int i = t; i < 68 * 68; i += 256) simp[i] = 0.f;
  if (t < 200) {
    int oc = t / 25, tap = t % 25;
    wls[tap * 8 + oc] = w[m * 200 + t];
  }
  if (t < 8) bls[t] = bias[m * 8 + t];
  const u16* fq = (m == 0) ? f1q : (m == 1) ? f2q : f3q;
  const u16* fc = (m == 0) ? f1c : (m == 1) ? f2c : f3c;
  const int D = 64 >> m;
  const int SEG = D >> 3;
  for (int i = t; i < 64 * SEG; i += 256) {
    int n = i / SEG, s = i - n * SEG;
    *(uint4*)&Qs[n * QS + s * 8] = *(const uint4*)&fq[(size_t)b * 64 * D + n * D + s * 8];
    *(uint4*)&Cs[n * QS + s * 8] = *(const uint4*)&fc[(size_t)b * 64 * D + n * D + s * 8];
  }
  if (m == 2 && t < 128) {
    int n = t >> 1, s = t & 1;
    uint4 z = {0u, 0u, 0u, 0u};
    *(uint4*)&Qs[n * QS + 16 + s * 8] = z;
    *(uint4*)&Cs[n * QS + 16 + s * 8] = z;
  }
  __syncthreads();
  const int w4 = t >> 6, lane = t & 63;
  const int r16 = lane & 15, kg = lane >> 4;
  const int Kpad = (m == 0) ? 64 : 32;
#pragma unroll 1
  for (int ct = 0; ct < 4; ++ct) {
    f32x4 acc = {0.f, 0.f, 0.f, 0.f};
    for (int ks = 0; ks < Kpad; ks += 32) {
      bf8v a = *(const bf8v*)&Qs[(w4 * 16 + r16) * QS + ks + kg * 8];
      bf8v bb = *(const bf8v*)&Cs[(ct * 16 + r16) * QS + ks + kg * 8];
      acc = __builtin_amdgcn_mfma_f32_16x16x32_bf16(a, bb, acc, 0, 0, 0);
    }
#pragma unroll
    for (int j = 0; j < 4; ++j)
      simp[(w4 * 16 + kg * 4 + j + 2) * PS + ct * 16 + r16 + 2] = acc[j];
  }
  __syncthreads();
  const int gy = t >> 4, gx = t & 15;
  float pr[8][8];
#pragma unroll
  for (int yy = 0; yy < 8; ++yy) {
    float4 a = *(const float4*)&simp[(4 * gy + yy) * PS + 4 * gx];
    float4 bb = *(const float4*)&simp[(4 * gy + yy) * PS + 4 * gx + 4];
    pr[yy][0] = a.x; pr[yy][1] = a.y; pr[yy][2] = a.z; pr[yy][3] = a.w;
    pr[yy][4] = bb.x; pr[yy][5] = bb.y; pr[yy][6] = bb.z; pr[yy][7] = bb.w;
  }
  u16* op = out + (size_t)(b * 3 + m) * 8192;
#pragma unroll 1
  for (int p2 = 0; p2 < 4; ++p2) {
    float acc[2][16];
#pragma unroll
    for (int p = 0; p < 16; ++p) { acc[0][p] = 0.f; acc[1][p] = 0.f; }
#pragma unroll
    for (int ky = 0; ky < 5; ++ky)
#pragma unroll
      for (int kx = 0; kx < 5; ++kx) {
        float2 wv = *(const float2*)&wls[(ky * 5 + kx) * 8 + p2 * 2];
#pragma unroll
        for (int dy = 0; dy < 4; ++dy)
#pragma unroll
          for (int dx = 0; dx < 4; ++dx) {
            float rv = pr[ky + dy][kx + dx];
            acc[0][dy * 4 + dx] += rv * wv.x;
            acc[1][dy * 4 + dx] += rv * wv.y;
          }
      }
    float b0 = bls[p2 * 2], b1 = bls[p2 * 2 + 1];
#pragma unroll
    for (int ay = 0; ay < 2; ++ay)
#pragma unroll
      for (int ax = 0; ax < 2; ++ax) {
        float v0 = fmaxf(fmaxf(acc[0][(2 * ay) * 4 + 2 * ax], acc[0][(2 * ay) * 4 + 2 * ax + 1]),
                         fmaxf(acc[0][(2 * ay + 1) * 4 + 2 * ax], acc[0][(2 * ay + 1) * 4 + 2 * ax + 1]));
        float v1 = fmaxf(fmaxf(acc[1][(2 * ay) * 4 + 2 * ax], acc[1][(2 * ay) * 4 + 2 * ax + 1]),
                         fmaxf(acc[1][(2 * ay + 1) * 4 + 2 * ax], acc[1][(2 * ay + 1) * 4 + 2 * ax + 1]));
        v0 = fmaxf(v0 + b0, 0.f);
        v1 = fmaxf(v1 + b1, 0.f);
        unsigned pack = (unsigned)f2bf(v0) | ((unsigned)f2bf(v1) << 16);
        *(unsigned*)&op[(size_t)(((2 * gy + ay) * 32) + (2 * gx + ax)) * 8 + p2 * 2] = pack;
      }
  }
}

// =================== prep: wcvt (blocks 0..383) + wprep (blocks 384..579) ===================
__global__ __launch_bounds__(256) void prep_kernel(
    const float* __restrict__ lw1, const float* __restrict__ cw2,
    const float* __restrict__ cw3, u16* __restrict__ wT,
    u16* __restrict__ w2p, u16* __restrict__ w3p) {
  const int t = threadIdx.x;
  if (blockIdx.x < 384) {
    __shared__ float tile[64][65];
    const int k0 = (blockIdx.x % 96) * 64, c0 = (blockIdx.x / 96) * 64;
    for (int i = t; i < 4096; i += 256) {
      int r = i >> 6, c = i & 63;
      tile[r][c] = lw1[(size_t)(k0 + r) * 256 + c0 + c];
    }
    __syncthreads();
    for (int i = t; i < 4096; i += 256) {
      int c = i >> 6, k = i & 63;
      wT[(size_t)(c0 + c) * 6144 + k0 + k] = f2bf(tile[k][c]);
    }
    return;
  }
  int i = (blockIdx.x - 384) * 256 + t;
  if (i < 3 * 7 * 16 * 40) {
    int m = i / 4480, r = i % 4480;
    int k = r % 40, rest = r / 40, oc = rest & 15, st = rest >> 4;
    u16 v = 0;
    if (k < 32) {
      int sl = k >> 3, ci = k & 7, tap = st * 4 + sl;
      if (tap < 25) v = f2bf(cw2[((size_t)(m * 16 + oc) * 8 + ci) * 25 + tap]);
    }
    w2p[i] = v;
  }
  if (i < 3 * 26 * 16 * 40) {
    int m = i / 16640, r = i % 16640;
    int k = r % 40, rest = r / 40, oc16 = rest & 15, sthalf = rest >> 4;
    int half = sthalf & 1, st = sthalf >> 1;
    u16 v = 0;
    if (k < 32) {
      int sl = k >> 4, ci = k & 15, tap = st * 2 + sl;
      int oc = half * 16 + oc16;
      if (tap < 25) v = f2bf(cw3[((size_t)(m * 32 + oc) * 16 + ci) * 25 + tap]);
    }
    w3p[i] = v;
  }
}

// =================== conv2+conv3 fused: conv2 output lives only in LDS ===================
// LDS union: phase A = {ins2 10368 u16 | w2ls 4480 u16} in uni[]; phase B = {w3ls 16640 u16} in uni[]
// persistent: p2s[20*20*16] (conv3's padded input layout), bls2, bls3. Total ~46.3 KB.
__global__ __launch_bounds__(256) void conv23_mfma(
    const u16* __restrict__ in, const u16* __restrict__ w2p,
    const float* __restrict__ cb2, const u16* __restrict__ w3p,
    const float* __restrict__ cb3, u16* __restrict__ feat) {
  constexpr int PW2 = 36, PW3 = 20, BS = 40;
  __shared__ __align__(16) u16 uni[16640];          // 33280 B
  __shared__ __align__(16) u16 p2s[PW3 * PW3 * 16]; // 12800 B
  __shared__ float bls2[16];
  __shared__ float bls3[32];
  const int b = blockIdx.x, m = blockIdx.y, t = threadIdx.x;
  u16* ins2 = uni;             // 10368 u16
  u16* w2ls = uni + 10368;     // 4480 u16 (byte off 20736, 16B aligned)
  // ---- phase A staging ----
  const size_t ibase = (size_t)(b * 3 + m) * 8192;
  for (int i = t; i < PW2 * PW2; i += 256) {
    int y = i / PW2, x = i % PW2;
    uint4 v = {0u, 0u, 0u, 0u};
    if (y >= 2 && y < 34 && x >= 2 && x < 34)
      v = *(const uint4*)&in[ibase + (size_t)((y - 2) * 32 + (x - 2)) * 8];
    *(uint4*)&ins2[i * 8] = v;
  }
  {
    const u16* wsrc = w2p + m * 4480;
    for (int i = t; i < 560; i += 256) *(uint4*)&w2ls[i * 8] = *(const uint4*)&wsrc[i * 8];
  }
  {
    uint4 z = {0u, 0u, 0u, 0u};
    for (int i = t; i < 800; i += 256) *(uint4*)&p2s[i * 8] = z;
  }
  if (t < 16) bls2[t] = cb2[m * 16 + t];
  if (t >= 32 && t < 64) bls3[t - 32] = cb3[m * 32 + (t - 32)];
  __syncthreads();
  // ---- phase A compute (conv2, identical math to round-11) ----
  const int wv = t >> 6, lane = t & 63;
  const int oc = lane & 15, g = lane >> 4;
  {
    const int xt = wv & 1, ypb = wv >> 1;
    const int x = xt * 16 + oc;
#pragma unroll 1
    for (int grp = 0; grp < 2; ++grp) {
      f32x4 acc[4][2];
#pragma unroll
      for (int i = 0; i < 4; ++i) {
        acc[i][0] = (f32x4){0.f, 0.f, 0.f, 0.f};
        acc[i][1] = (f32x4){0.f, 0.f, 0.f, 0.f};
      }
#pragma unroll
      for (int st = 0; st < 7; ++st) {
        bf8v bvv = *(const bf8v*)&w2ls[(st * 16 + oc) * BS + g * 8];
        const int c0 = cmin(st * 4 + 0, 24), c1 = cmin(st * 4 + 1, 24);
        const int c2 = cmin(st * 4 + 2, 24), c3 = cmin(st * 4 + 3, 24);
        const int k0 = (c0 / 5) * PW2 + c0 % 5, k1 = (c1 / 5) * PW2 + c1 % 5;
        const int k2 = (c2 / 5) * PW2 + c2 % 5, k3 = (c3 / 5) * PW2 + c3 % 5;
        const int koff = (g == 0) ? k0 : (g == 1) ? k1 : (g == 2) ? k2 : k3;
#pragma unroll
        for (int i = 0; i < 4; ++i) {
          const int y0 = 2 * ypb + 4 * (grp * 4 + i);
          const int abase = (y0 * PW2 + x + koff) * 8;
          bf8v a0 = *(const bf8v*)&ins2[abase];
          acc[i][0] = __builtin_amdgcn_mfma_f32_16x16x32_bf16(a0, bvv, acc[i][0], 0, 0, 0);
          bf8v a1 = *(const bf8v*)&ins2[abase + PW2 * 8];
          acc[i][1] = __builtin_amdgcn_mfma_f32_16x16x32_bf16(a1, bvv, acc[i][1], 0, 0, 0);
        }
      }
      const float bb = bls2[oc];
#pragma unroll
      for (int i = 0; i < 4; ++i) {
        const int yp = ypb + 2 * (grp * 4 + i);
        const float v0 = fmaxf(fmaxf(fmaxf(acc[i][0][0], acc[i][0][1]),
                                     fmaxf(acc[i][1][0], acc[i][1][1])) + bb, 0.f);
        const float v1 = fmaxf(fmaxf(fmaxf(acc[i][0][2], acc[i][0][3]),
                                     fmaxf(acc[i][1][2], acc[i][1][3])) + bb, 0.f);
        const int px = xt * 8 + 2 * g;
        p2s[((yp + 2) * PW3 + (px + 2)) * 16 + oc] = f2bf(v0);
        p2s[((yp + 2) * PW3 + (px + 3)) * 16 + oc] = f2bf(v1);
      }
    }
  }
  __syncthreads();  // phase A fully done (all ins2/w2ls reads + p2s writes)
  // ---- phase B staging: w3 overwrites uni ----
  {
    const u16* wsrc = w3p + m * 16640;
    for (int i = t; i < 2080; i += 256) *(uint4*)&uni[i * 8] = *(const uint4*)&wsrc[i * 8];
  }
  __syncthreads();
  // ---- phase B compute (conv3, identical math to round-11) ----
  {
    const int sl = g >> 1, ch = (g & 1) * 8;
    const int half = wv & 1, ypb = wv >> 1;
    u16* fb = feat + (size_t)b * 6144 + m * 2048;
    f32x4 acc[4][2];
#pragma unroll
    for (int i = 0; i < 4; ++i) {
      acc[i][0] = (f32x4){0.f, 0.f, 0.f, 0.f};
      acc[i][1] = (f32x4){0.f, 0.f, 0.f, 0.f};
    }
#pragma unroll
    for (int st = 0; st < 13; ++st) {
      bf8v bvv = *(const bf8v*)&uni[(size_t)((st * 2 + half) * 16 + oc) * BS + g * 8];
      const int c0 = cmin(st * 2 + 0, 24), c1 = cmin(st * 2 + 1, 24);
      const int k0 = (c0 / 5) * PW3 + c0 % 5, k1 = (c1 / 5) * PW3 + c1 % 5;
      const int koff = sl ? k1 : k0;
#pragma unroll
      for (int i = 0; i < 4; ++i) {
        const int y0 = 2 * ypb + 4 * i;
        const int abase = (y0 * PW3 + oc + koff) * 16 + ch;
        bf8v a0 = *(const bf8v*)&p2s[abase];
        acc[i][0] = __builtin_amdgcn_mfma_f32_16x16x32_bf16(a0, bvv, acc[i][0], 0, 0, 0);
        bf8v a1 = *(const bf8v*)&p2s[abase + PW3 * 16];
        acc[i][1] = __builtin_amdgcn_mfma_f32_16x16x32_bf16(a1, bvv, acc[i][1], 0, 0, 0);
      }
    }
    const int ocg = half * 16 + oc;
    const float bb = bls3[ocg];
#pragma unroll
    for (int i = 0; i < 4; ++i) {
      const int yp = ypb + 2 * i;
      const float v0 = fmaxf(fmaxf(fmaxf(acc[i][0][0], acc[i][0][1]),
                                   fmaxf(acc[i][1][0], acc[i][1][1])) + bb, 0.f);
      const float v1 = fmaxf(fmaxf(fmaxf(acc[i][0][2], acc[i][0][3]),
                                   fmaxf(acc[i][1][2], acc[i][1][3])) + bb, 0.f);
      unsigned pack = (unsigned)f2bf(v0) | ((unsigned)f2bf(v1) << 16);
      *(unsigned*)&fb[ocg * 64 + yp * 8 + 2 * g] = pack;
    }
  }
}

// =================== lin1: bf16 MFMA GEMM (unchanged) ===================
__global__ __launch_bounds__(256) void lin1_mfma(const u16* __restrict__ feat,
                                                 const u16* __restrict__ wT,
                                                 float* __restrict__ h1p) {
  constexpr int AS = 72;
  __shared__ __align__(16) u16 As[64 * AS];
  __shared__ __align__(16) u16 Bs[64 * AS];
  const int r0 = blockIdx.x * 64, c0 = blockIdx.y * 64, kb = blockIdx.z * 384;
  const int t = threadIdx.x;
  const int w = t >> 6, lane = t & 63;
  const int row16 = lane & 15, kg = lane >> 4;
  f32x4 acc[4] = {{0.f, 0.f, 0.f, 0.f}, {0.f, 0.f, 0.f, 0.f},
                  {0.f, 0.f, 0.f, 0.f}, {0.f, 0.f, 0.f, 0.f}};
  const int lr = t >> 2, lk = (t & 3) * 16;
#pragma unroll 1
  for (int st = 0; st < 6; ++st) {
    __syncthreads();
    const int ks = kb + st * 64;
    {
      const u16* srcA = feat + (size_t)(r0 + lr) * 6144 + ks + lk;
      uint4 a0 = *(const uint4*)srcA;
      uint4 a1 = *(const uint4*)(srcA + 8);
      *(uint4*)&As[lr * AS + lk] = a0;
      *(uint4*)&As[lr * AS + lk + 8] = a1;
      const u16* srcB = wT + (size_t)(c0 + lr) * 6144 + ks + lk;
      uint4 b0 = *(const uint4*)srcB;
      uint4 b1 = *(const uint4*)(srcB + 8);
      *(uint4*)&Bs[lr * AS + lk] = b0;
      *(uint4*)&Bs[lr * AS + lk + 8] = b1;
    }
    __syncthreads();
#pragma unroll
    for (int kk = 0; kk < 2; ++kk) {
      bf8v a = *(const bf8v*)&As[(w * 16 + row16) * AS + kk * 32 + kg * 8];
#pragma unroll
      for (int ct = 0; ct < 4; ++ct) {
        bf8v bb = *(const bf8v*)&Bs[(ct * 16 + row16) * AS + kk * 32 + kg * 8];
        acc[ct] = __builtin_amdgcn_mfma_f32_16x16x32_bf16(a, bb, acc[ct], 0, 0, 0);
      }
    }
  }
  float* out = h1p + (size_t)blockIdx.z * 131072;
#pragma unroll
  for (int ct = 0; ct < 4; ++ct)
#pragma unroll
    for (int j = 0; j < 4; ++j)
      out[(size_t)(r0 + w * 16 + kg * 4 + j) * 256 + c0 + ct * 16 + row16] = acc[ct][j];
}

// =================== head (unchanged) ===================
__global__ __launch_bounds__(256) void head_kernel(
    const float* __restrict__ h1p, const float* __restrict__ b1,
    const float* __restrict__ w2, const float* __restrict__ b2,
    const float* __restrict__ sw, const float* __restrict__ sb,
    float* __restrict__ out) {
  constexpr int HS = 260;
  __shared__ __align__(16) float h1s[16 * HS];
  __shared__ __align__(16) float w2s[256 * 16];
  const int r0 = blockIdx.x * 16, t = threadIdx.x;
  for (int i = t; i < 4096; i += 256) {
    int r = i >> 8, k = i & 255;
    float s = b1[k];
#pragma unroll
    for (int p = 0; p < 16; ++p) s += h1p[(size_t)p * 131072 + (size_t)(r0 + r) * 256 + k];
    h1s[r * HS + k] = s;
    w2s[i] = w2[i];
  }
  __syncthreads();
  const int j = t & 15, r = t >> 4;
  float acc = b2[j];
#pragma unroll 4
  for (int k4 = 0; k4 < 64; ++k4) {
    float4 hv = *(const float4*)&h1s[r * HS + 4 * k4];
    float h0 = fmaxf(hv.x, 0.f), h1v = fmaxf(hv.y, 0.f);
    float h2v = fmaxf(hv.z, 0.f), h3 = fmaxf(hv.w, 0.f);
    acc += h0 * w2s[(4 * k4 + 0) * 16 + j];
    acc += h1v * w2s[(4 * k4 + 1) * 16 + j];
    acc += h2v * w2s[(4 * k4 + 2) * 16 + j];
    acc += h3 * w2s[(4 * k4 + 3) * 16 + j];
  }
  float v = fmaxf(acc, 0.f) * sw[j];
#pragma unroll
  for (int off = 8; off; off >>= 1) v += __shfl_xor(v, off, 16);
  if (j == 0) out[r0 + r] = v + sb[0];
}

// =================== launcher ===================
extern "C" void kernel_launch(void* const* d_in, const int* in_sizes, int n_in,
                              void* d_out, int out_size, void* d_ws, size_t ws_size,
                              hipStream_t stream) {
  const float* x_q = (const float*)d_in[0];
  const float* x_c = (const float*)d_in[1];
  const int* edge_q = (const int*)d_in[2];
  const int* edge_c = (const int*)d_in[3];
  const float* gw1 = (const float*)d_in[4];
  const float* gb1 = (const float*)d_in[5];
  const float* gw2 = (const float*)d_in[6];
  const float* gb2 = (const float*)d_in[7];
  const float* gw3 = (const float*)d_in[8];
  const float* gb3 = (const float*)d_in[9];
  const float* cw1 = (const float*)d_in[10];
  const float* cb1 = (const float*)d_in[11];
  const float* cw2 = (const float*)d_in[12];
  const float* cb2 = (const float*)d_in[13];
  const float* cw3 = (const float*)d_in[14];
  const float* cb3 = (const float*)d_in[15];
  const float* lw1 = (const float*)d_in[16];
  const float* lb1 = (const float*)d_in[17];
  const float* lw2 = (const float*)d_in[18];
  const float* lb2 = (const float*)d_in[19];
  const float* swt = (const float*)d_in[20];
  const float* sbs = (const float*)d_in[21];
  float* ws = (float*)d_ws;

  const size_t o_f1q = 65536;
  const size_t o_f2q = o_f1q + 2097152;
  const size_t o_f3q = o_f2q + 1048576;
  const size_t o_f1c = o_f3q + 524288;
  const size_t o_f2c = o_f1c + 2097152;
  const size_t o_f3c = o_f2c + 1048576;
  const size_t o_sims = o_f3c + 524288;
  const size_t o_pm1 = o_sims + 6291456;
  const size_t o_pm2 = o_pm1 + 6291456;  // now unused (kept for layout stability)
  const size_t o_wT = o_pm2 + 3145728;
  const size_t o_w2p = o_wT + 786432;
  const size_t o_w3p = o_w2p + 8192;
  const size_t o_feat = o_sims;           // bf16 feat
  const size_t o_h1p = o_f1q;             // reuse (f1q dead after simconv1)

  u16* f1q = (u16*)(ws + o_f1q); u16* f2q = (u16*)(ws + o_f2q); u16* f3q = (u16*)(ws + o_f3q);
  u16* f1c = (u16*)(ws + o_f1c); u16* f2c = (u16*)(ws + o_f2c); u16* f3c = (u16*)(ws + o_f3c);
  u16* pm1 = (u16*)(ws + o_pm1);
  u16* wT = (u16*)(ws + o_wT);
  u16* w2p = (u16*)(ws + o_w2p);
  u16* w3p = (u16*)(ws + o_w3p);
  u16* feat = (u16*)(ws + o_feat);
  float* h1p = ws + o_h1p;

  prep_kernel<<<580, 256, 0, stream>>>(lw1, cw2, cw3, wT, w2p, w3p);

  gcn_fused<<<dim3(B, 2), 512, 0, stream>>>(x_q, x_c, gw1, gb1, gw2, gb2, gw3, gb3,
                                            edge_q, edge_c, f1q, f1c, f2q, f2c, f3q, f3c);

  simconv1<<<dim3(B, 3), 256, 0, stream>>>(f1q, f1c, f2q, f2c, f3q, f3c, cw1, cb1, pm1);

  conv23_mfma<<<dim3(B, 3), 256, 0, stream>>>(pm1, w2p, cb2, w3p, cb3, feat);

  lin1_mfma<<<dim3(8, 4, 16), 256, 0, stream>>>(feat, wT, h1p);
  head_kernel<<<32, 256, 0, stream>>>(h1p, lb1, lw2, lb2, swt, sbs, (float*)d_out);
}

// Round 14
// 131.021 us; speedup vs baseline: 1.4916x; 1.0005x over previous
//
#include <hip/hip_runtime.h>
#include <hip/hip_bf16.h>

constexpr int B = 512, N = 64, E = 512, NE = B * E;

typedef __attribute__((ext_vector_type(8))) short bf8v;
typedef __attribute__((ext_vector_type(4))) float f32x4;
typedef __attribute__((ext_vector_type(2))) float v2f;
typedef unsigned short u16;

__device__ __forceinline__ u16 f2bf(float f) {
  unsigned u = __builtin_bit_cast(unsigned, f);
  u += 0x7FFFu + ((u >> 16) & 1u);
  return (u16)(u >> 16);
}

__device__ __forceinline__ int cmin(int a, int b) { return a < b ? a : b; }

// =================== fused 3-layer GCN: 512 threads, unroll 8 ===================
template <int DIN, int DOUT, int NR, int NC, bool STORE_NEXT>
__device__ __forceinline__ void gcn_layer(
    float* __restrict__ At, float* __restrict__ Xt, float* __restrict__ Hs,
    const float* __restrict__ W, const float* __restrict__ bias,
    u16* __restrict__ fout, int g, int t) {
  constexpr int XS = 68;
  constexpr int CT = DOUT / NC;
  static_assert((64 / NR) * CT == 512, "thread mapping");
  const int ct = t % CT, nt = t / CT;
  const int n0 = NR * nt, c0 = NC * ct;
  {
    float acc[NR][NC] = {};
#pragma unroll 8
    for (int k = 0; k < DIN; ++k) {
      float xa[NR];
      if constexpr (NR == 4) {
        float4 xv = *(const float4*)&Xt[k * XS + n0];
        xa[0] = xv.x; xa[1] = xv.y; xa[2] = xv.z; xa[3] = xv.w;
      } else {
        float2 xv = *(const float2*)&Xt[k * XS + n0];
        xa[0] = xv.x; xa[1] = xv.y;
      }
      float wa[NC];
      if constexpr (NC == 2) {
        float2 wv = *(const float2*)&W[k * DOUT + c0];
        wa[0] = wv.x; wa[1] = wv.y;
      } else {
        wa[0] = W[k * DOUT + c0];
      }
#pragma unroll
      for (int i = 0; i < NR; ++i)
#pragma unroll
        for (int j = 0; j < NC; ++j) acc[i][j] += xa[i] * wa[j];
    }
#pragma unroll
    for (int i = 0; i < NR; ++i) {
      if constexpr (NC == 2)
        *(float2*)&Hs[(n0 + i) * XS + c0] = make_float2(acc[i][0], acc[i][1]);
      else
        Hs[(n0 + i) * XS + c0] = acc[i][0];
    }
  }
  __syncthreads();
  {
    float acc[NR][NC] = {};
#pragma unroll 8
    for (int s = 0; s < N; ++s) {
      float aa[NR];
      if constexpr (NR == 4) {
        float4 av = *(const float4*)&At[s * XS + n0];
        aa[0] = av.x; aa[1] = av.y; aa[2] = av.z; aa[3] = av.w;
      } else {
        float2 av = *(const float2*)&At[s * XS + n0];
        aa[0] = av.x; aa[1] = av.y;
      }
      float ha[NC];
      if constexpr (NC == 2) {
        float2 hv = *(const float2*)&Hs[s * XS + c0];
        ha[0] = hv.x; ha[1] = hv.y;
      } else {
        ha[0] = Hs[s * XS + c0];
      }
#pragma unroll
      for (int i = 0; i < NR; ++i)
#pragma unroll
        for (int j = 0; j < NC; ++j) acc[i][j] += aa[i] * ha[j];
    }
    float bv[NC];
#pragma unroll
    for (int j = 0; j < NC; ++j) bv[j] = bias[c0 + j];
#pragma unroll
    for (int i = 0; i < NR; ++i) {
      float st[NC];
#pragma unroll
      for (int j = 0; j < NC; ++j) st[j] = acc[i][j] + bv[j];
      if constexpr (NC == 2) {
        unsigned pack = (unsigned)f2bf(st[0]) | ((unsigned)f2bf(st[1]) << 16);
        *(unsigned*)&fout[(size_t)g * N * DOUT + (size_t)(n0 + i) * DOUT + c0] = pack;
      } else {
        fout[(size_t)g * N * DOUT + (size_t)(n0 + i) * DOUT + c0] = f2bf(st[0]);
      }
      if (STORE_NEXT) {
#pragma unroll
        for (int j = 0; j < NC; ++j)
          Xt[(c0 + j) * XS + n0 + i] = fmaxf(st[j], 0.f);
      }
    }
  }
  __syncthreads();
}

__global__ __launch_bounds__(512) void gcn_fused(
    const float* __restrict__ xq, const float* __restrict__ xc,
    const float* __restrict__ W1, const float* __restrict__ b1,
    const float* __restrict__ W2, const float* __restrict__ b2,
    const float* __restrict__ W3, const float* __restrict__ b3,
    const int* __restrict__ eq, const int* __restrict__ ec,
    u16* __restrict__ f1q, u16* __restrict__ f1c,
    u16* __restrict__ f2q, u16* __restrict__ f2c,
    u16* __restrict__ f3q, u16* __restrict__ f3c) {
  constexpr int XS = 68;
  __shared__ __align__(16) float At[N * XS];
  __shared__ __align__(16) float Xt[N * XS];
  __shared__ __align__(16) float Hs[N * XS];
  __shared__ float dl[N];
  __shared__ int cnt[N];
  const int g = blockIdx.x, t = threadIdx.x;
  const float* x = blockIdx.y ? xc : xq;
  const int* edges = blockIdx.y ? ec : eq;
  u16* o1 = blockIdx.y ? f1c : f1q;
  u16* o2 = blockIdx.y ? f2c : f2q;
  u16* o3 = blockIdx.y ? f3c : f3q;
  for (int i = t; i < N * 16; i += 512) {
    int n = i / 16, k = i % 16;
    Xt[k * XS + n] = x[(size_t)g * N * 16 + i];
  }
  for (int i = t; i < N * XS; i += 512) At[i] = 0.f;
  if (t < N) cnt[t] = 1;
  __syncthreads();
  const int* srcp = edges + (size_t)g * E;
  const int* dstp = edges + NE + (size_t)g * E;
  for (int j = t; j < E; j += 512) atomicAdd(&cnt[dstp[j] & 63], 1);
  __syncthreads();
  if (t < N) dl[t] = rsqrtf((float)cnt[t]);
  __syncthreads();
  for (int j = t; j < E; j += 512) {
    int s = srcp[j] & 63, d = dstp[j] & 63;
    atomicAdd(&At[s * XS + d], dl[s] * dl[d]);
  }
  if (t < N) atomicAdd(&At[t * XS + t], dl[t] * dl[t]);
  __syncthreads();
  gcn_layer<16, 64, 4, 2, true>(At, Xt, Hs, W1, b1, o1, g, t);
  gcn_layer<64, 32, 4, 1, true>(At, Xt, Hs, W2, b2, o2, g, t);
  gcn_layer<32, 16, 2, 1, false>(At, Xt, Hs, W3, b3, o3, g, t);
}

// =================== fused sim (bf16 MFMA) + conv1 (pk-fma fp32, oc-pairs) ===================
__global__ __launch_bounds__(256) void simconv1(
    const u16* __restrict__ f1q, const u16* __restrict__ f1c,
    const u16* __restrict__ f2q, const u16* __restrict__ f2c,
    const u16* __restrict__ f3q, const u16* __restrict__ f3c,
    const float* __restrict__ w, const float* __restrict__ bias,
    u16* __restrict__ out) {
  constexpr int PS = 68, QS = 72;
  __shared__ __align__(16) u16 Qs[64 * QS];
  __shared__ __align__(16) u16 Cs[64 * QS];
  __shared__ __align__(16) float simp[68 * 68];
  __shared__ float wls[25 * 8];  // [tap][oc]
  __shared__ float bls[8];
  const int b = blockIdx.x, m = blockIdx.y, t = threadIdx.x;
  for (int i = t; i < 68 * 68; i += 256) simp[i] = 0.f;
  if (t < 200) {
    int oc = t / 25, tap = t % 25;
    wls[tap * 8 + oc] = w[m * 200 + t];
  }
  if (t < 8) bls[t] = bias[m * 8 + t];
  const u16* fq = (m == 0) ? f1q : (m == 1) ? f2q : f3q;
  const u16* fc = (m == 0) ? f1c : (m == 1) ? f2c : f3c;
  const int D = 64 >> m;
  const int SEG = D >> 3;
  for (int i = t; i < 64 * SEG; i += 256) {
    int n = i / SEG, s = i - n * SEG;
    *(uint4*)&Qs[n * QS + s * 8] = *(const uint4*)&fq[(size_t)b * 64 * D + n * D + s * 8];
    *(uint4*)&Cs[n * QS + s * 8] = *(const uint4*)&fc[(size_t)b * 64 * D + n * D + s * 8];
  }
  if (m == 2 && t < 128) {
    int n = t >> 1, s = t & 1;
    uint4 z = {0u, 0u, 0u, 0u};
    *(uint4*)&Qs[n * QS + 16 + s * 8] = z;
    *(uint4*)&Cs[n * QS + 16 + s * 8] = z;
  }
  __syncthreads();
  const int w4 = t >> 6, lane = t & 63;
  const int r16 = lane & 15, kg = lane >> 4;
  const int Kpad = (m == 0) ? 64 : 32;
#pragma unroll 1
  for (int ct = 0; ct < 4; ++ct) {
    f32x4 acc = {0.f, 0.f, 0.f, 0.f};
    for (int ks = 0; ks < Kpad; ks += 32) {
      bf8v a = *(const bf8v*)&Qs[(w4 * 16 + r16) * QS + ks + kg * 8];
      bf8v bb = *(const bf8v*)&Cs[(ct * 16 + r16) * QS + ks + kg * 8];
      acc = __builtin_amdgcn_mfma_f32_16x16x32_bf16(a, bb, acc, 0, 0, 0);
    }
#pragma unroll
    for (int j = 0; j < 4; ++j)
      simp[(w4 * 16 + kg * 4 + j + 2) * PS + ct * 16 + r16 + 2] = acc[j];
  }
  __syncthreads();
  const int gy = t >> 4, gx = t & 15;
  float pr[8][8];
#pragma unroll
  for (int yy = 0; yy < 8; ++yy) {
    float4 a = *(const float4*)&simp[(4 * gy + yy) * PS + 4 * gx];
    float4 bb = *(const float4*)&simp[(4 * gy + yy) * PS + 4 * gx + 4];
    pr[yy][0] = a.x; pr[yy][1] = a.y; pr[yy][2] = a.z; pr[yy][3] = a.w;
    pr[yy][4] = bb.x; pr[yy][5] = bb.y; pr[yy][6] = bb.z; pr[yy][7] = bb.w;
  }
  u16* op = out + (size_t)(b * 3 + m) * 8192;
#pragma unroll 1
  for (int p2 = 0; p2 < 4; ++p2) {
    v2f accp[16];
#pragma unroll
    for (int p = 0; p < 16; ++p) accp[p] = (v2f){0.f, 0.f};
#pragma unroll
    for (int ky = 0; ky < 5; ++ky)
#pragma unroll
      for (int kx = 0; kx < 5; ++kx) {
        v2f wv = __builtin_bit_cast(v2f, *(const float2*)&wls[(ky * 5 + kx) * 8 + p2 * 2]);
#pragma unroll
        for (int dy = 0; dy < 4; ++dy)
#pragma unroll
          for (int dx = 0; dx < 4; ++dx)
            accp[dy * 4 + dx] += wv * pr[ky + dy][kx + dx];
      }
    const float b0 = bls[p2 * 2], b1 = bls[p2 * 2 + 1];
#pragma unroll
    for (int ay = 0; ay < 2; ++ay)
#pragma unroll
      for (int ax = 0; ax < 2; ++ax) {
        float v0 = fmaxf(fmaxf(accp[(2 * ay) * 4 + 2 * ax][0], accp[(2 * ay) * 4 + 2 * ax + 1][0]),
                         fmaxf(accp[(2 * ay + 1) * 4 + 2 * ax][0], accp[(2 * ay + 1) * 4 + 2 * ax + 1][0]));
        float v1 = fmaxf(fmaxf(accp[(2 * ay) * 4 + 2 * ax][1], accp[(2 * ay) * 4 + 2 * ax + 1][1]),
                         fmaxf(accp[(2 * ay + 1) * 4 + 2 * ax][1], accp[(2 * ay + 1) * 4 + 2 * ax + 1][1]));
        v0 = fmaxf(v0 + b0, 0.f);
        v1 = fmaxf(v1 + b1, 0.f);
        unsigned pack = (unsigned)f2bf(v0) | ((unsigned)f2bf(v1) << 16);
        *(unsigned*)&op[(size_t)(((2 * gy + ay) * 32) + (2 * gx + ax)) * 8 + p2 * 2] = pack;
      }
  }
}

// =================== prep: wcvt (blocks 0..383) + wprep (blocks 384..579) ===================
__global__ __launch_bounds__(256) void prep_kernel(
    const float* __restrict__ lw1, const float* __restrict__ cw2,
    const float* __restrict__ cw3, u16* __restrict__ wT,
    u16* __restrict__ w2p, u16* __restrict__ w3p) {
  const int t = threadIdx.x;
  if (blockIdx.x < 384) {
    __shared__ float tile[64][65];
    const int k0 = (blockIdx.x % 96) * 64, c0 = (blockIdx.x / 96) * 64;
    for (int i = t; i < 4096; i += 256) {
      int r = i >> 6, c = i & 63;
      tile[r][c] = lw1[(size_t)(k0 + r) * 256 + c0 + c];
    }
    __syncthreads();
    for (int i = t; i < 4096; i += 256) {
      int c = i >> 6, k = i & 63;
      wT[(size_t)(c0 + c) * 6144 + k0 + k] = f2bf(tile[k][c]);
    }
    return;
  }
  int i = (blockIdx.x - 384) * 256 + t;
  if (i < 3 * 7 * 16 * 40) {
    int m = i / 4480, r = i % 4480;
    int k = r % 40, rest = r / 40, oc = rest & 15, st = rest >> 4;
    u16 v = 0;
    if (k < 32) {
      int sl = k >> 3, ci = k & 7, tap = st * 4 + sl;
      if (tap < 25) v = f2bf(cw2[((size_t)(m * 16 + oc) * 8 + ci) * 25 + tap]);
    }
    w2p[i] = v;
  }
  if (i < 3 * 26 * 16 * 40) {
    int m = i / 16640, r = i % 16640;
    int k = r % 40, rest = r / 40, oc16 = rest & 15, sthalf = rest >> 4;
    int half = sthalf & 1, st = sthalf >> 1;
    u16 v = 0;
    if (k < 32) {
      int sl = k >> 4, ci = k & 15, tap = st * 2 + sl;
      int oc = half * 16 + oc16;
      if (tap < 25) v = f2bf(cw3[((size_t)(m * 32 + oc) * 16 + ci) * 25 + tap]);
    }
    w3p[i] = v;
  }
}

// =================== conv2+conv3 fused (unchanged from round-13) ===================
__global__ __launch_bounds__(256) void conv23_mfma(
    const u16* __restrict__ in, const u16* __restrict__ w2p,
    const float* __restrict__ cb2, const u16* __restrict__ w3p,
    const float* __restrict__ cb3, u16* __restrict__ feat) {
  constexpr int PW2 = 36, PW3 = 20, BS = 40;
  __shared__ __align__(16) u16 uni[16640];
  __shared__ __align__(16) u16 p2s[PW3 * PW3 * 16];
  __shared__ float bls2[16];
  __shared__ float bls3[32];
  const int b = blockIdx.x, m = blockIdx.y, t = threadIdx.x;
  u16* ins2 = uni;
  u16* w2ls = uni + 10368;
  const size_t ibase = (size_t)(b * 3 + m) * 8192;
  for (int i = t; i < PW2 * PW2; i += 256) {
    int y = i / PW2, x = i % PW2;
    uint4 v = {0u, 0u, 0u, 0u};
    if (y >= 2 && y < 34 && x >= 2 && x < 34)
      v = *(const uint4*)&in[ibase + (size_t)((y - 2) * 32 + (x - 2)) * 8];
    *(uint4*)&ins2[i * 8] = v;
  }
  {
    const u16* wsrc = w2p + m * 4480;
    for (int i = t; i < 560; i += 256) *(uint4*)&w2ls[i * 8] = *(const uint4*)&wsrc[i * 8];
  }
  {
    uint4 z = {0u, 0u, 0u, 0u};
    for (int i = t; i < 800; i += 256) *(uint4*)&p2s[i * 8] = z;
  }
  if (t < 16) bls2[t] = cb2[m * 16 + t];
  if (t >= 32 && t < 64) bls3[t - 32] = cb3[m * 32 + (t - 32)];
  __syncthreads();
  const int wv = t >> 6, lane = t & 63;
  const int oc = lane & 15, g = lane >> 4;
  {
    const int xt = wv & 1, ypb = wv >> 1;
    const int x = xt * 16 + oc;
#pragma unroll 1
    for (int grp = 0; grp < 2; ++grp) {
      f32x4 acc[4][2];
#pragma unroll
      for (int i = 0; i < 4; ++i) {
        acc[i][0] = (f32x4){0.f, 0.f, 0.f, 0.f};
        acc[i][1] = (f32x4){0.f, 0.f, 0.f, 0.f};
      }
#pragma unroll
      for (int st = 0; st < 7; ++st) {
        bf8v bvv = *(const bf8v*)&w2ls[(st * 16 + oc) * BS + g * 8];
        const int c0 = cmin(st * 4 + 0, 24), c1 = cmin(st * 4 + 1, 24);
        const int c2 = cmin(st * 4 + 2, 24), c3 = cmin(st * 4 + 3, 24);
        const int k0 = (c0 / 5) * PW2 + c0 % 5, k1 = (c1 / 5) * PW2 + c1 % 5;
        const int k2 = (c2 / 5) * PW2 + c2 % 5, k3 = (c3 / 5) * PW2 + c3 % 5;
        const int koff = (g == 0) ? k0 : (g == 1) ? k1 : (g == 2) ? k2 : k3;
#pragma unroll
        for (int i = 0; i < 4; ++i) {
          const int y0 = 2 * ypb + 4 * (grp * 4 + i);
          const int abase = (y0 * PW2 + x + koff) * 8;
          bf8v a0 = *(const bf8v*)&ins2[abase];
          acc[i][0] = __builtin_amdgcn_mfma_f32_16x16x32_bf16(a0, bvv, acc[i][0], 0, 0, 0);
          bf8v a1 = *(const bf8v*)&ins2[abase + PW2 * 8];
          acc[i][1] = __builtin_amdgcn_mfma_f32_16x16x32_bf16(a1, bvv, acc[i][1], 0, 0, 0);
        }
      }
      const float bb = bls2[oc];
#pragma unroll
      for (int i = 0; i < 4; ++i) {
        const int yp = ypb + 2 * (grp * 4 + i);
        const float v0 = fmaxf(fmaxf(fmaxf(acc[i][0][0], acc[i][0][1]),
                                     fmaxf(acc[i][1][0], acc[i][1][1])) + bb, 0.f);
        const float v1 = fmaxf(fmaxf(fmaxf(acc[i][0][2], acc[i][0][3]),
                                     fmaxf(acc[i][1][2], acc[i][1][3])) + bb, 0.f);
        const int px = xt * 8 + 2 * g;
        p2s[((yp + 2) * PW3 + (px + 2)) * 16 + oc] = f2bf(v0);
        p2s[((yp + 2) * PW3 + (px + 3)) * 16 + oc] = f2bf(v1);
      }
    }
  }
  __syncthreads();
  {
    const u16* wsrc = w3p + m * 16640;
    for (int i = t; i < 2080; i += 256) *(uint4*)&uni[i * 8] = *(const uint4*)&wsrc[i * 8];
  }
  __syncthreads();
  {
    const int sl = g >> 1, ch = (g & 1) * 8;
    const int half = wv & 1, ypb = wv >> 1;
    u16* fb = feat + (size_t)b * 6144 + m * 2048;
    f32x4 acc[4][2];
#pragma unroll
    for (int i = 0; i < 4; ++i) {
      acc[i][0] = (f32x4){0.f, 0.f, 0.f, 0.f};
      acc[i][1] = (f32x4){0.f, 0.f, 0.f, 0.f};
    }
#pragma unroll
    for (int st = 0; st < 13; ++st) {
      bf8v bvv = *(const bf8v*)&uni[(size_t)((st * 2 + half) * 16 + oc) * BS + g * 8];
      const int c0 = cmin(st * 2 + 0, 24), c1 = cmin(st * 2 + 1, 24);
      const int k0 = (c0 / 5) * PW3 + c0 % 5, k1 = (c1 / 5) * PW3 + c1 % 5;
      const int koff = sl ? k1 : k0;
#pragma unroll
      for (int i = 0; i < 4; ++i) {
        const int y0 = 2 * ypb + 4 * i;
        const int abase = (y0 * PW3 + oc + koff) * 16 + ch;
        bf8v a0 = *(const bf8v*)&p2s[abase];
        acc[i][0] = __builtin_amdgcn_mfma_f32_16x16x32_bf16(a0, bvv, acc[i][0], 0, 0, 0);
        bf8v a1 = *(const bf8v*)&p2s[abase + PW3 * 16];
        acc[i][1] = __builtin_amdgcn_mfma_f32_16x16x32_bf16(a1, bvv, acc[i][1], 0, 0, 0);
      }
    }
    const int ocg = half * 16 + oc;
    const float bb = bls3[ocg];
#pragma unroll
    for (int i = 0; i < 4; ++i) {
      const int yp = ypb + 2 * i;
      const float v0 = fmaxf(fmaxf(fmaxf(acc[i][0][0], acc[i][0][1]),
                                   fmaxf(acc[i][1][0], acc[i][1][1])) + bb, 0.f);
      const float v1 = fmaxf(fmaxf(fmaxf(acc[i][0][2], acc[i][0][3]),
                                   fmaxf(acc[i][1][2], acc[i][1][3])) + bb, 0.f);
      unsigned pack = (unsigned)f2bf(v0) | ((unsigned)f2bf(v1) << 16);
      *(unsigned*)&fb[ocg * 64 + yp * 8 + 2 * g] = pack;
    }
  }
}

// =================== lin1: bf16 MFMA GEMM (unchanged) ===================
__global__ __launch_bounds__(256) void lin1_mfma(const u16* __restrict__ feat,
                                                 const u16* __restrict__ wT,
                                                 float* __restrict__ h1p) {
  constexpr int AS = 72;
  __shared__ __align__(16) u16 As[64 * AS];
  __shared__ __align__(16) u16 Bs[64 * AS];
  const int r0 = blockIdx.x * 64, c0 = blockIdx.y * 64, kb = blockIdx.z * 384;
  const int t = threadIdx.x;
  const int w = t >> 6, lane = t & 63;
  const int row16 = lane & 15, kg = lane >> 4;
  f32x4 acc[4] = {{0.f, 0.f, 0.f, 0.f}, {0.f, 0.f, 0.f, 0.f},
                  {0.f, 0.f, 0.f, 0.f}, {0.f, 0.f, 0.f, 0.f}};
  const int lr = t >> 2, lk = (t & 3) * 16;
#pragma unroll 1
  for (int st = 0; st < 6; ++st) {
    __syncthreads();
    const int ks = kb + st * 64;
    {
      const u16* srcA = feat + (size_t)(r0 + lr) * 6144 + ks + lk;
      uint4 a0 = *(const uint4*)srcA;
      uint4 a1 = *(const uint4*)(srcA + 8);
      *(uint4*)&As[lr * AS + lk] = a0;
      *(uint4*)&As[lr * AS + lk + 8] = a1;
      const u16* srcB = wT + (size_t)(c0 + lr) * 6144 + ks + lk;
      uint4 b0 = *(const uint4*)srcB;
      uint4 b1 = *(const uint4*)(srcB + 8);
      *(uint4*)&Bs[lr * AS + lk] = b0;
      *(uint4*)&Bs[lr * AS + lk + 8] = b1;
    }
    __syncthreads();
#pragma unroll
    for (int kk = 0; kk < 2; ++kk) {
      bf8v a = *(const bf8v*)&As[(w * 16 + row16) * AS + kk * 32 + kg * 8];
#pragma unroll
      for (int ct = 0; ct < 4; ++ct) {
        bf8v bb = *(const bf8v*)&Bs[(ct * 16 + row16) * AS + kk * 32 + kg * 8];
        acc[ct] = __builtin_amdgcn_mfma_f32_16x16x32_bf16(a, bb, acc[ct], 0, 0, 0);
      }
    }
  }
  float* out = h1p + (size_t)blockIdx.z * 131072;
#pragma unroll
  for (int ct = 0; ct < 4; ++ct)
#pragma unroll
    for (int j = 0; j < 4; ++j)
      out[(size_t)(r0 + w * 16 + kg * 4 + j) * 256 + c0 + ct * 16 + row16] = acc[ct][j];
}

// =================== head (unchanged) ===================
__global__ __launch_bounds__(256) void head_kernel(
    const float* __restrict__ h1p, const float* __restrict__ b1,
    const float* __restrict__ w2, const float* __restrict__ b2,
    const float* __restrict__ sw, const float* __restrict__ sb,
    float* __restrict__ out) {
  constexpr int HS = 260;
  __shared__ __align__(16) float h1s[16 * HS];
  __shared__ __align__(16) float w2s[256 * 16];
  const int r0 = blockIdx.x * 16, t = threadIdx.x;
  for (int i = t; i < 4096; i += 256) {
    int r = i >> 8, k = i & 255;
    float s = b1[k];
#pragma unroll
    for (int p = 0; p < 16; ++p) s += h1p[(size_t)p * 131072 + (size_t)(r0 + r) * 256 + k];
    h1s[r * HS + k] = s;
    w2s[i] = w2[i];
  }
  __syncthreads();
  const int j = t & 15, r = t >> 4;
  float acc = b2[j];
#pragma unroll 4
  for (int k4 = 0; k4 < 64; ++k4) {
    float4 hv = *(const float4*)&h1s[r * HS + 4 * k4];
    float h0 = fmaxf(hv.x, 0.f), h1v = fmaxf(hv.y, 0.f);
    float h2v = fmaxf(hv.z, 0.f), h3 = fmaxf(hv.w, 0.f);
    acc += h0 * w2s[(4 * k4 + 0) * 16 + j];
    acc += h1v * w2s[(4 * k4 + 1) * 16 + j];
    acc += h2v * w2s[(4 * k4 + 2) * 16 + j];
    acc += h3 * w2s[(4 * k4 + 3) * 16 + j];
  }
  float v = fmaxf(acc, 0.f) * sw[j];
#pragma unroll
  for (int off = 8; off; off >>= 1) v += __shfl_xor(v, off, 16);
  if (j == 0) out[r0 + r] = v + sb[0];
}

// =================== launcher ===================
extern "C" void kernel_launch(void* const* d_in, const int* in_sizes, int n_in,
                              void* d_out, int out_size, void* d_ws, size_t ws_size,
                              hipStream_t stream) {
  const float* x_q = (const float*)d_in[0];
  const float* x_c = (const float*)d_in[1];
  const int* edge_q = (const int*)d_in[2];
  const int* edge_c = (const int*)d_in[3];
  const float* gw1 = (const float*)d_in[4];
  const float* gb1 = (const float*)d_in[5];
  const float* gw2 = (const float*)d_in[6];
  const float* gb2 = (const float*)d_in[7];
  const float* gw3 = (const float*)d_in[8];
  const float* gb3 = (const float*)d_in[9];
  const float* cw1 = (const float*)d_in[10];
  const float* cb1 = (const float*)d_in[11];
  const float* cw2 = (const float*)d_in[12];
  const float* cb2 = (const float*)d_in[13];
  const float* cw3 = (const float*)d_in[14];
  const float* cb3 = (const float*)d_in[15];
  const float* lw1 = (const float*)d_in[16];
  const float* lb1 = (const float*)d_in[17];
  const float* lw2 = (const float*)d_in[18];
  const float* lb2 = (const float*)d_in[19];
  const float* swt = (const float*)d_in[20];
  const float* sbs = (const float*)d_in[21];
  float* ws = (float*)d_ws;

  const size_t o_f1q = 65536;
  const size_t o_f2q = o_f1q + 2097152;
  const size_t o_f3q = o_f2q + 1048576;
  const size_t o_f1c = o_f3q + 524288;
  const size_t o_f2c = o_f1c + 2097152;
  const size_t o_f3c = o_f2c + 1048576;
  const size_t o_sims = o_f3c + 524288;
  const size_t o_pm1 = o_sims + 6291456;
  const size_t o_pm2 = o_pm1 + 6291456;
  const size_t o_wT = o_pm2 + 3145728;
  const size_t o_w2p = o_wT + 786432;
  const size_t o_w3p = o_w2p + 8192;
  const size_t o_feat = o_sims;
  const size_t o_h1p = o_f1q;

  u16* f1q = (u16*)(ws + o_f1q); u16* f2q = (u16*)(ws + o_f2q); u16* f3q = (u16*)(ws + o_f3q);
  u16* f1c = (u16*)(ws + o_f1c); u16* f2c = (u16*)(ws + o_f2c); u16* f3c = (u16*)(ws + o_f3c);
  u16* pm1 = (u16*)(ws + o_pm1);
  u16* wT = (u16*)(ws + o_wT);
  u16* w2p = (u16*)(ws + o_w2p);
  u16* w3p = (u16*)(ws + o_w3p);
  u16* feat = (u16*)(ws + o_feat);
  float* h1p = ws + o_h1p;

  prep_kernel<<<580, 256, 0, stream>>>(lw1, cw2, cw3, wT, w2p, w3p);

  gcn_fused<<<dim3(B, 2), 512, 0, stream>>>(x_q, x_c, gw1, gb1, gw2, gb2, gw3, gb3,
                                            edge_q, edge_c, f1q, f1c, f2q, f2c, f3q, f3c);

  simconv1<<<dim3(B, 3), 256, 0, stream>>>(f1q, f1c, f2q, f2c, f3q, f3c, cw1, cb1, pm1);

  conv23_mfma<<<dim3(B, 3), 256, 0, stream>>>(pm1, w2p, cb2, w3p, cb3, feat);

  lin1_mfma<<<dim3(8, 4, 16), 256, 0, stream>>>(feat, wT, h1p);
  head_kernel<<<32, 256, 0, stream>>>(h1p, lb1, lw2, lb2, swt, sbs, (float*)d_out);
}

// Round 15
// 130.955 us; speedup vs baseline: 1.4923x; 1.0005x over previous
//
#include <hip/hip_runtime.h>
#include <hip/hip_bf16.h>

constexpr int B = 512, N = 64, E = 512, NE = B * E;

typedef __attribute__((ext_vector_type(8))) short bf8v;
typedef __attribute__((ext_vector_type(4))) float f32x4;
typedef unsigned short u16;

__device__ __forceinline__ u16 f2bf(float f) {
  unsigned u = __builtin_bit_cast(unsigned, f);
  u += 0x7FFFu + ((u >> 16) & 1u);
  return (u16)(u >> 16);
}

__device__ __forceinline__ int cmin(int a, int b) { return a < b ? a : b; }

// =================== fused 3-layer GCN: 512 threads, all-thread layers ===================
template <int DIN, int DOUT, int NR, int NC, bool STORE_NEXT>
__device__ __forceinline__ void gcn_layer(
    float* __restrict__ At, float* __restrict__ Xt, float* __restrict__ Hs,
    const float* __restrict__ W, const float* __restrict__ bias,
    u16* __restrict__ fout, int g, int t) {
  constexpr int XS = 68;
  constexpr int CT = DOUT / NC;
  static_assert((64 / NR) * CT == 512, "thread mapping");
  const int ct = t % CT, nt = t / CT;
  const int n0 = NR * nt, c0 = NC * ct;
  {
    float acc[NR][NC] = {};
#pragma unroll 4
    for (int k = 0; k < DIN; ++k) {
      float xa[NR];
      if constexpr (NR == 4) {
        float4 xv = *(const float4*)&Xt[k * XS + n0];
        xa[0] = xv.x; xa[1] = xv.y; xa[2] = xv.z; xa[3] = xv.w;
      } else {
        float2 xv = *(const float2*)&Xt[k * XS + n0];
        xa[0] = xv.x; xa[1] = xv.y;
      }
      float wa[NC];
      if constexpr (NC == 2) {
        float2 wv = *(const float2*)&W[k * DOUT + c0];
        wa[0] = wv.x; wa[1] = wv.y;
      } else {
        wa[0] = W[k * DOUT + c0];
      }
#pragma unroll
      for (int i = 0; i < NR; ++i)
#pragma unroll
        for (int j = 0; j < NC; ++j) acc[i][j] += xa[i] * wa[j];
    }
#pragma unroll
    for (int i = 0; i < NR; ++i) {
      if constexpr (NC == 2)
        *(float2*)&Hs[(n0 + i) * XS + c0] = make_float2(acc[i][0], acc[i][1]);
      else
        Hs[(n0 + i) * XS + c0] = acc[i][0];
    }
  }
  __syncthreads();
  {
    float acc[NR][NC] = {};
#pragma unroll 4
    for (int s = 0; s < N; ++s) {
      float aa[NR];
      if constexpr (NR == 4) {
        float4 av = *(const float4*)&At[s * XS + n0];
        aa[0] = av.x; aa[1] = av.y; aa[2] = av.z; aa[3] = av.w;
      } else {
        float2 av = *(const float2*)&At[s * XS + n0];
        aa[0] = av.x; aa[1] = av.y;
      }
      float ha[NC];
      if constexpr (NC == 2) {
        float2 hv = *(const float2*)&Hs[s * XS + c0];
        ha[0] = hv.x; ha[1] = hv.y;
      } else {
        ha[0] = Hs[s * XS + c0];
      }
#pragma unroll
      for (int i = 0; i < NR; ++i)
#pragma unroll
        for (int j = 0; j < NC; ++j) acc[i][j] += aa[i] * ha[j];
    }
    float bv[NC];
#pragma unroll
    for (int j = 0; j < NC; ++j) bv[j] = bias[c0 + j];
#pragma unroll
    for (int i = 0; i < NR; ++i) {
      float st[NC];
#pragma unroll
      for (int j = 0; j < NC; ++j) st[j] = acc[i][j] + bv[j];
      if constexpr (NC == 2) {
        unsigned pack = (unsigned)f2bf(st[0]) | ((unsigned)f2bf(st[1]) << 16);
        *(unsigned*)&fout[(size_t)g * N * DOUT + (size_t)(n0 + i) * DOUT + c0] = pack;
      } else {
        fout[(size_t)g * N * DOUT + (size_t)(n0 + i) * DOUT + c0] = f2bf(st[0]);
      }
      if (STORE_NEXT) {
#pragma unroll
        for (int j = 0; j < NC; ++j)
          Xt[(c0 + j) * XS + n0 + i] = fmaxf(st[j], 0.f);
      }
    }
  }
  __syncthreads();
}

__global__ __launch_bounds__(512) void gcn_fused(
    const float* __restrict__ xq, const float* __restrict__ xc,
    const float* __restrict__ W1, const float* __restrict__ b1,
    const float* __restrict__ W2, const float* __restrict__ b2,
    const float* __restrict__ W3, const float* __restrict__ b3,
    const int* __restrict__ eq, const int* __restrict__ ec,
    u16* __restrict__ f1q, u16* __restrict__ f1c,
    u16* __restrict__ f2q, u16* __restrict__ f2c,
    u16* __restrict__ f3q, u16* __restrict__ f3c) {
  constexpr int XS = 68;
  __shared__ __align__(16) float At[N * XS];
  __shared__ __align__(16) float Xt[N * XS];
  __shared__ __align__(16) float Hs[N * XS];
  __shared__ float dl[N];
  __shared__ int cnt[N];
  const int g = blockIdx.x, t = threadIdx.x;
  const float* x = blockIdx.y ? xc : xq;
  const int* edges = blockIdx.y ? ec : eq;
  u16* o1 = blockIdx.y ? f1c : f1q;
  u16* o2 = blockIdx.y ? f2c : f2q;
  u16* o3 = blockIdx.y ? f3c : f3q;
  for (int i = t; i < N * 16; i += 512) {
    int n = i / 16, k = i % 16;
    Xt[k * XS + n] = x[(size_t)g * N * 16 + i];
  }
  for (int i = t; i < N * XS; i += 512) At[i] = 0.f;
  if (t < N) cnt[t] = 1;
  __syncthreads();
  const int* srcp = edges + (size_t)g * E;
  const int* dstp = edges + NE + (size_t)g * E;
  for (int j = t; j < E; j += 512) atomicAdd(&cnt[dstp[j] & 63], 1);
  __syncthreads();
  if (t < N) dl[t] = rsqrtf((float)cnt[t]);
  __syncthreads();
  for (int j = t; j < E; j += 512) {
    int s = srcp[j] & 63, d = dstp[j] & 63;
    atomicAdd(&At[s * XS + d], dl[s] * dl[d]);
  }
  if (t < N) atomicAdd(&At[t * XS + t], dl[t] * dl[t]);
  __syncthreads();
  gcn_layer<16, 64, 4, 2, true>(At, Xt, Hs, W1, b1, o1, g, t);
  gcn_layer<64, 32, 4, 1, true>(At, Xt, Hs, W2, b2, o2, g, t);
  gcn_layer<32, 16, 2, 1, false>(At, Xt, Hs, W3, b3, o3, g, t);
}

// =================== fused sim (bf16 MFMA) + conv1 (fp32 VALU, oc-pairs) ===================
__global__ __launch_bounds__(256, 4) void simconv1(
    const u16* __restrict__ f1q, const u16* __restrict__ f1c,
    const u16* __restrict__ f2q, const u16* __restrict__ f2c,
    const u16* __restrict__ f3q, const u16* __restrict__ f3c,
    const float* __restrict__ w, const float* __restrict__ bias,
    u16* __restrict__ out) {
  constexpr int PS = 68, QS = 72;
  __shared__ __align__(16) u16 Qs[64 * QS];
  __shared__ __align__(16) u16 Cs[64 * QS];
  __shared__ __align__(16) float simp[68 * 68];
  __shared__ float wls[25 * 8];  // [tap][oc]
  __shared__ float bls[8];
  const int b = blockIdx.x, m = blockIdx.y, t = threadIdx.x;
  for (int i = t; i < 68 * 68; i += 256) simp[i] = 0.f;
  if (t < 200) {
    int oc = t / 25, tap = t % 25;
    wls[tap * 8 + oc] = w[m * 200 + t];
  }
  if (t < 8) bls[t] = bias[m * 8 + t];
  const u16* fq = (m == 0) ? f1q : (m == 1) ? f2q : f3q;
  const u16* fc = (m == 0) ? f1c : (m == 1) ? f2c : f3c;
  const int D = 64 >> m;
  const int SEG = D >> 3;
  for (int i = t; i < 64 * SEG; i += 256) {
    int n = i / SEG, s = i - n * SEG;
    *(uint4*)&Qs[n * QS + s * 8] = *(const uint4*)&fq[(size_t)b * 64 * D + n * D + s * 8];
    *(uint4*)&Cs[n * QS + s * 8] = *(const uint4*)&fc[(size_t)b * 64 * D + n * D + s * 8];
  }
  if (m == 2 && t < 128) {
    int n = t >> 1, s = t & 1;
    uint4 z = {0u, 0u, 0u, 0u};
    *(uint4*)&Qs[n * QS + 16 + s * 8] = z;
    *(uint4*)&Cs[n * QS + 16 + s * 8] = z;
  }
  __syncthreads();
  const int w4 = t >> 6, lane = t & 63;
  const int r16 = lane & 15, kg = lane >> 4;
  const int Kpad = (m == 0) ? 64 : 32;
#pragma unroll 1
  for (int ct = 0; ct < 4; ++ct) {
    f32x4 acc = {0.f, 0.f, 0.f, 0.f};
    for (int ks = 0; ks < Kpad; ks += 32) {
      bf8v a = *(const bf8v*)&Qs[(w4 * 16 + r16) * QS + ks + kg * 8];
      bf8v bb = *(const bf8v*)&Cs[(ct * 16 + r16) * QS + ks + kg * 8];
      acc = __builtin_amdgcn_mfma_f32_16x16x32_bf16(a, bb, acc, 0, 0, 0);
    }
#pragma unroll
    for (int j = 0; j < 4; ++j)
      simp[(w4 * 16 + kg * 4 + j + 2) * PS + ct * 16 + r16 + 2] = acc[j];
  }
  __syncthreads();
  const int gy = t >> 4, gx = t & 15;
  float pr[8][8];
#pragma unroll
  for (int yy = 0; yy < 8; ++yy) {
    float4 a = *(const float4*)&simp[(4 * gy + yy) * PS + 4 * gx];
    float4 bb = *(const float4*)&simp[(4 * gy + yy) * PS + 4 * gx + 4];
    pr[yy][0] = a.x; pr[yy][1] = a.y; pr[yy][2] = a.z; pr[yy][3] = a.w;
    pr[yy][4] = bb.x; pr[yy][5] = bb.y; pr[yy][6] = bb.z; pr[yy][7] = bb.w;
  }
  u16* op = out + (size_t)(b * 3 + m) * 8192;
#pragma unroll 1
  for (int p2 = 0; p2 < 4; ++p2) {
    float acc[2][16];
#pragma unroll
    for (int p = 0; p < 16; ++p) { acc[0][p] = 0.f; acc[1][p] = 0.f; }
#pragma unroll
    for (int ky = 0; ky < 5; ++ky)
#pragma unroll
      for (int kx = 0; kx < 5; ++kx) {
        float2 wv = *(const float2*)&wls[(ky * 5 + kx) * 8 + p2 * 2];
#pragma unroll
        for (int dy = 0; dy < 4; ++dy)
#pragma unroll
          for (int dx = 0; dx < 4; ++dx) {
            float rv = pr[ky + dy][kx + dx];
            acc[0][dy * 4 + dx] += rv * wv.x;
            acc[1][dy * 4 + dx] += rv * wv.y;
          }
      }
    float b0 = bls[p2 * 2], b1 = bls[p2 * 2 + 1];
#pragma unroll
    for (int ay = 0; ay < 2; ++ay)
#pragma unroll
      for (int ax = 0; ax < 2; ++ax) {
        float v0 = fmaxf(fmaxf(acc[0][(2 * ay) * 4 + 2 * ax], acc[0][(2 * ay) * 4 + 2 * ax + 1]),
                         fmaxf(acc[0][(2 * ay + 1) * 4 + 2 * ax], acc[0][(2 * ay + 1) * 4 + 2 * ax + 1]));
        float v1 = fmaxf(fmaxf(acc[1][(2 * ay) * 4 + 2 * ax], acc[1][(2 * ay) * 4 + 2 * ax + 1]),
                         fmaxf(acc[1][(2 * ay + 1) * 4 + 2 * ax], acc[1][(2 * ay + 1) * 4 + 2 * ax + 1]));
        v0 = fmaxf(v0 + b0, 0.f);
        v1 = fmaxf(v1 + b1, 0.f);
        unsigned pack = (unsigned)f2bf(v0) | ((unsigned)f2bf(v1) << 16);
        *(unsigned*)&op[(size_t)(((2 * gy + ay) * 32) + (2 * gx + ax)) * 8 + p2 * 2] = pack;
      }
  }
}

// =================== prep: wcvt (blocks 0..383) + wprep (blocks 384..579) ===================
__global__ __launch_bounds__(256) void prep_kernel(
    const float* __restrict__ lw1, const float* __restrict__ cw2,
    const float* __restrict__ cw3, u16* __restrict__ wT,
    u16* __restrict__ w2p, u16* __restrict__ w3p) {
  const int t = threadIdx.x;
  if (blockIdx.x < 384) {
    __shared__ float tile[64][65];
    const int k0 = (blockIdx.x % 96) * 64, c0 = (blockIdx.x / 96) * 64;
    for (int i = t; i < 4096; i += 256) {
      int r = i >> 6, c = i & 63;
      tile[r][c] = lw1[(size_t)(k0 + r) * 256 + c0 + c];
    }
    __syncthreads();
    for (int i = t; i < 4096; i += 256) {
      int c = i >> 6, k = i & 63;
      wT[(size_t)(c0 + c) * 6144 + k0 + k] = f2bf(tile[k][c]);
    }
    return;
  }
  int i = (blockIdx.x - 384) * 256 + t;
  if (i < 3 * 7 * 16 * 40) {
    int m = i / 4480, r = i % 4480;
    int k = r % 40, rest = r / 40, oc = rest & 15, st = rest >> 4;
    u16 v = 0;
    if (k < 32) {
      int sl = k >> 3, ci = k & 7, tap = st * 4 + sl;
      if (tap < 25) v = f2bf(cw2[((size_t)(m * 16 + oc) * 8 + ci) * 25 + tap]);
    }
    w2p[i] = v;
  }
  if (i < 3 * 26 * 16 * 40) {
    int m = i / 16640, r = i % 16640;
    int k = r % 40, rest = r / 40, oc16 = rest & 15, sthalf = rest >> 4;
    int half = sthalf & 1, st = sthalf >> 1;
    u16 v = 0;
    if (k < 32) {
      int sl = k >> 4, ci = k & 15, tap = st * 2 + sl;
      int oc = half * 16 + oc16;
      if (tap < 25) v = f2bf(cw3[((size_t)(m * 32 + oc) * 16 + ci) * 25 + tap]);
    }
    w3p[i] = v;
  }
}

// =================== conv2+conv3 fused, with s_setprio around MFMA clusters ===================
__global__ __launch_bounds__(256) void conv23_mfma(
    const u16* __restrict__ in, const u16* __restrict__ w2p,
    const float* __restrict__ cb2, const u16* __restrict__ w3p,
    const float* __restrict__ cb3, u16* __restrict__ feat) {
  constexpr int PW2 = 36, PW3 = 20, BS = 40;
  __shared__ __align__(16) u16 uni[16640];
  __shared__ __align__(16) u16 p2s[PW3 * PW3 * 16];
  __shared__ float bls2[16];
  __shared__ float bls3[32];
  const int b = blockIdx.x, m = blockIdx.y, t = threadIdx.x;
  u16* ins2 = uni;
  u16* w2ls = uni + 10368;
  const size_t ibase = (size_t)(b * 3 + m) * 8192;
  for (int i = t; i < PW2 * PW2; i += 256) {
    int y = i / PW2, x = i % PW2;
    uint4 v = {0u, 0u, 0u, 0u};
    if (y >= 2 && y < 34 && x >= 2 && x < 34)
      v = *(const uint4*)&in[ibase + (size_t)((y - 2) * 32 + (x - 2)) * 8];
    *(uint4*)&ins2[i * 8] = v;
  }
  {
    const u16* wsrc = w2p + m * 4480;
    for (int i = t; i < 560; i += 256) *(uint4*)&w2ls[i * 8] = *(const uint4*)&wsrc[i * 8];
  }
  {
    uint4 z = {0u, 0u, 0u, 0u};
    for (int i = t; i < 800; i += 256) *(uint4*)&p2s[i * 8] = z;
  }
  if (t < 16) bls2[t] = cb2[m * 16 + t];
  if (t >= 32 && t < 64) bls3[t - 32] = cb3[m * 32 + (t - 32)];
  __syncthreads();
  const int wv = t >> 6, lane = t & 63;
  const int oc = lane & 15, g = lane >> 4;
  {
    const int xt = wv & 1, ypb = wv >> 1;
    const int x = xt * 16 + oc;
    __builtin_amdgcn_s_setprio(1);
#pragma unroll 1
    for (int grp = 0; grp < 2; ++grp) {
      f32x4 acc[4][2];
#pragma unroll
      for (int i = 0; i < 4; ++i) {
        acc[i][0] = (f32x4){0.f, 0.f, 0.f, 0.f};
        acc[i][1] = (f32x4){0.f, 0.f, 0.f, 0.f};
      }
#pragma unroll
      for (int st = 0; st < 7; ++st) {
        bf8v bvv = *(const bf8v*)&w2ls[(st * 16 + oc) * BS + g * 8];
        const int c0 = cmin(st * 4 + 0, 24), c1 = cmin(st * 4 + 1, 24);
        const int c2 = cmin(st * 4 + 2, 24), c3 = cmin(st * 4 + 3, 24);
        const int k0 = (c0 / 5) * PW2 + c0 % 5, k1 = (c1 / 5) * PW2 + c1 % 5;
        const int k2 = (c2 / 5) * PW2 + c2 % 5, k3 = (c3 / 5) * PW2 + c3 % 5;
        const int koff = (g == 0) ? k0 : (g == 1) ? k1 : (g == 2) ? k2 : k3;
#pragma unroll
        for (int i = 0; i < 4; ++i) {
          const int y0 = 2 * ypb + 4 * (grp * 4 + i);
          const int abase = (y0 * PW2 + x + koff) * 8;
          bf8v a0 = *(const bf8v*)&ins2[abase];
          acc[i][0] = __builtin_amdgcn_mfma_f32_16x16x32_bf16(a0, bvv, acc[i][0], 0, 0, 0);
          bf8v a1 = *(const bf8v*)&ins2[abase + PW2 * 8];
          acc[i][1] = __builtin_amdgcn_mfma_f32_16x16x32_bf16(a1, bvv, acc[i][1], 0, 0, 0);
        }
      }
      const float bb = bls2[oc];
#pragma unroll
      for (int i = 0; i < 4; ++i) {
        const int yp = ypb + 2 * (grp * 4 + i);
        const float v0 = fmaxf(fmaxf(fmaxf(acc[i][0][0], acc[i][0][1]),
                                     fmaxf(acc[i][1][0], acc[i][1][1])) + bb, 0.f);
        const float v1 = fmaxf(fmaxf(fmaxf(acc[i][0][2], acc[i][0][3]),
                                     fmaxf(acc[i][1][2], acc[i][1][3])) + bb, 0.f);
        const int px = xt * 8 + 2 * g;
        p2s[((yp + 2) * PW3 + (px + 2)) * 16 + oc] = f2bf(v0);
        p2s[((yp + 2) * PW3 + (px + 3)) * 16 + oc] = f2bf(v1);
      }
    }
    __builtin_amdgcn_s_setprio(0);
  }
  __syncthreads();
  {
    const u16* wsrc = w3p + m * 16640;
    for (int i = t; i < 2080; i += 256) *(uint4*)&uni[i * 8] = *(const uint4*)&wsrc[i * 8];
  }
  __syncthreads();
  {
    const int sl = g >> 1, ch = (g & 1) * 8;
    const int half = wv & 1, ypb = wv >> 1;
    u16* fb = feat + (size_t)b * 6144 + m * 2048;
    f32x4 acc[4][2];
#pragma unroll
    for (int i = 0; i < 4; ++i) {
      acc[i][0] = (f32x4){0.f, 0.f, 0.f, 0.f};
      acc[i][1] = (f32x4){0.f, 0.f, 0.f, 0.f};
    }
    __builtin_amdgcn_s_setprio(1);
#pragma unroll
    for (int st = 0; st < 13; ++st) {
      bf8v bvv = *(const bf8v*)&uni[(size_t)((st * 2 + half) * 16 + oc) * BS + g * 8];
      const int c0 = cmin(st * 2 + 0, 24), c1 = cmin(st * 2 + 1, 24);
      const int k0 = (c0 / 5) * PW3 + c0 % 5, k1 = (c1 / 5) * PW3 + c1 % 5;
      const int koff = sl ? k1 : k0;
#pragma unroll
      for (int i = 0; i < 4; ++i) {
        const int y0 = 2 * ypb + 4 * i;
        const int abase = (y0 * PW3 + oc + koff) * 16 + ch;
        bf8v a0 = *(const bf8v*)&p2s[abase];
        acc[i][0] = __builtin_amdgcn_mfma_f32_16x16x32_bf16(a0, bvv, acc[i][0], 0, 0, 0);
        bf8v a1 = *(const bf8v*)&p2s[abase + PW3 * 16];
        acc[i][1] = __builtin_amdgcn_mfma_f32_16x16x32_bf16(a1, bvv, acc[i][1], 0, 0, 0);
      }
    }
    __builtin_amdgcn_s_setprio(0);
    const int ocg = half * 16 + oc;
    const float bb = bls3[ocg];
#pragma unroll
    for (int i = 0; i < 4; ++i) {
      const int yp = ypb + 2 * i;
      const float v0 = fmaxf(fmaxf(fmaxf(acc[i][0][0], acc[i][0][1]),
                                   fmaxf(acc[i][1][0], acc[i][1][1])) + bb, 0.f);
      const float v1 = fmaxf(fmaxf(fmaxf(acc[i][0][2], acc[i][0][3]),
                                   fmaxf(acc[i][1][2], acc[i][1][3])) + bb, 0.f);
      unsigned pack = (unsigned)f2bf(v0) | ((unsigned)f2bf(v1) << 16);
      *(unsigned*)&fb[ocg * 64 + yp * 8 + 2 * g] = pack;
    }
  }
}

// =================== lin1: bf16 MFMA GEMM (unchanged) ===================
__global__ __launch_bounds__(256) void lin1_mfma(const u16* __restrict__ feat,
                                                 const u16* __restrict__ wT,
                                                 float* __restrict__ h1p) {
  constexpr int AS = 72;
  __shared__ __align__(16) u16 As[64 * AS];
  __shared__ __align__(16) u16 Bs[64 * AS];
  const int r0 = blockIdx.x * 64, c0 = blockIdx.y * 64, kb = blockIdx.z * 384;
  const int t = threadIdx.x;
  const int w = t >> 6, lane = t & 63;
  const int row16 = lane & 15, kg = lane >> 4;
  f32x4 acc[4] = {{0.f, 0.f, 0.f, 0.f}, {0.f, 0.f, 0.f, 0.f},
                  {0.f, 0.f, 0.f, 0.f}, {0.f, 0.f, 0.f, 0.f}};
  const int lr = t >> 2, lk = (t & 3) * 16;
#pragma unroll 1
  for (int st = 0; st < 6; ++st) {
    __syncthreads();
    const int ks = kb + st * 64;
    {
      const u16* srcA = feat + (size_t)(r0 + lr) * 6144 + ks + lk;
      uint4 a0 = *(const uint4*)srcA;
      uint4 a1 = *(const uint4*)(srcA + 8);
      *(uint4*)&As[lr * AS + lk] = a0;
      *(uint4*)&As[lr * AS + lk + 8] = a1;
      const u16* srcB = wT + (size_t)(c0 + lr) * 6144 + ks + lk;
      uint4 b0 = *(const uint4*)srcB;
      uint4 b1 = *(const uint4*)(srcB + 8);
      *(uint4*)&Bs[lr * AS + lk] = b0;
      *(uint4*)&Bs[lr * AS + lk + 8] = b1;
    }
    __syncthreads();
#pragma unroll
    for (int kk = 0; kk < 2; ++kk) {
      bf8v a = *(const bf8v*)&As[(w * 16 + row16) * AS + kk * 32 + kg * 8];
#pragma unroll
      for (int ct = 0; ct < 4; ++ct) {
        bf8v bb = *(const bf8v*)&Bs[(ct * 16 + row16) * AS + kk * 32 + kg * 8];
        acc[ct] = __builtin_amdgcn_mfma_f32_16x16x32_bf16(a, bb, acc[ct], 0, 0, 0);
      }
    }
  }
  float* out = h1p + (size_t)blockIdx.z * 131072;
#pragma unroll
  for (int ct = 0; ct < 4; ++ct)
#pragma unroll
    for (int j = 0; j < 4; ++j)
      out[(size_t)(r0 + w * 16 + kg * 4 + j) * 256 + c0 + ct * 16 + row16] = acc[ct][j];
}

// =================== head (unchanged) ===================
__global__ __launch_bounds__(256) void head_kernel(
    const float* __restrict__ h1p, const float* __restrict__ b1,
    const float* __restrict__ w2, const float* __restrict__ b2,
    const float* __restrict__ sw, const float* __restrict__ sb,
    float* __restrict__ out) {
  constexpr int HS = 260;
  __shared__ __align__(16) float h1s[16 * HS];
  __shared__ __align__(16) float w2s[256 * 16];
  const int r0 = blockIdx.x * 16, t = threadIdx.x;
  for (int i = t; i < 4096; i += 256) {
    int r = i >> 8, k = i & 255;
    float s = b1[k];
#pragma unroll
    for (int p = 0; p < 16; ++p) s += h1p[(size_t)p * 131072 + (size_t)(r0 + r) * 256 + k];
    h1s[r * HS + k] = s;
    w2s[i] = w2[i];
  }
  __syncthreads();
  const int j = t & 15, r = t >> 4;
  float acc = b2[j];
#pragma unroll 4
  for (int k4 = 0; k4 < 64; ++k4) {
    float4 hv = *(const float4*)&h1s[r * HS + 4 * k4];
    float h0 = fmaxf(hv.x, 0.f), h1v = fmaxf(hv.y, 0.f);
    float h2v = fmaxf(hv.z, 0.f), h3 = fmaxf(hv.w, 0.f);
    acc += h0 * w2s[(4 * k4 + 0) * 16 + j];
    acc += h1v * w2s[(4 * k4 + 1) * 16 + j];
    acc += h2v * w2s[(4 * k4 + 2) * 16 + j];
    acc += h3 * w2s[(4 * k4 + 3) * 16 + j];
  }
  float v = fmaxf(acc, 0.f) * sw[j];
#pragma unroll
  for (int off = 8; off; off >>= 1) v += __shfl_xor(v, off, 16);
  if (j == 0) out[r0 + r] = v + sb[0];
}

// =================== launcher ===================
extern "C" void kernel_launch(void* const* d_in, const int* in_sizes, int n_in,
                              void* d_out, int out_size, void* d_ws, size_t ws_size,
                              hipStream_t stream) {
  const float* x_q = (const float*)d_in[0];
  const float* x_c = (const float*)d_in[1];
  const int* edge_q = (const int*)d_in[2];
  const int* edge_c = (const int*)d_in[3];
  const float* gw1 = (const float*)d_in[4];
  const float* gb1 = (const float*)d_in[5];
  const float* gw2 = (const float*)d_in[6];
  const float* gb2 = (const float*)d_in[7];
  const float* gw3 = (const float*)d_in[8];
  const float* gb3 = (const float*)d_in[9];
  const float* cw1 = (const float*)d_in[10];
  const float* cb1 = (const float*)d_in[11];
  const float* cw2 = (const float*)d_in[12];
  const float* cb2 = (const float*)d_in[13];
  const float* cw3 = (const float*)d_in[14];
  const float* cb3 = (const float*)d_in[15];
  const float* lw1 = (const float*)d_in[16];
  const float* lb1 = (const float*)d_in[17];
  const float* lw2 = (const float*)d_in[18];
  const float* lb2 = (const float*)d_in[19];
  const float* swt = (const float*)d_in[20];
  const float* sbs = (const float*)d_in[21];
  float* ws = (float*)d_ws;

  const size_t o_f1q = 65536;
  const size_t o_f2q = o_f1q + 2097152;
  const size_t o_f3q = o_f2q + 1048576;
  const size_t o_f1c = o_f3q + 524288;
  const size_t o_f2c = o_f1c + 2097152;
  const size_t o_f3c = o_f2c + 1048576;
  const size_t o_sims = o_f3c + 524288;
  const size_t o_pm1 = o_sims + 6291456;
  const size_t o_pm2 = o_pm1 + 6291456;
  const size_t o_wT = o_pm2 + 3145728;
  const size_t o_w2p = o_wT + 786432;
  const size_t o_w3p = o_w2p + 8192;
  const size_t o_feat = o_sims;
  const size_t o_h1p = o_f1q;

  u16* f1q = (u16*)(ws + o_f1q); u16* f2q = (u16*)(ws + o_f2q); u16* f3q = (u16*)(ws + o_f3q);
  u16* f1c = (u16*)(ws + o_f1c); u16* f2c = (u16*)(ws + o_f2c); u16* f3c = (u16*)(ws + o_f3c);
  u16* pm1 = (u16*)(ws + o_pm1);
  u16* wT = (u16*)(ws + o_wT);
  u16* w2p = (u16*)(ws + o_w2p);
  u16* w3p = (u16*)(ws + o_w3p);
  u16* feat = (u16*)(ws + o_feat);
  float* h1p = ws + o_h1p;

  prep_kernel<<<580, 256, 0, stream>>>(lw1, cw2, cw3, wT, w2p, w3p);

  gcn_fused<<<dim3(B, 2), 512, 0, stream>>>(x_q, x_c, gw1, gb1, gw2, gb2, gw3, gb3,
                                            edge_q, edge_c, f1q, f1c, f2q, f2c, f3q, f3c);

  simconv1<<<dim3(B, 3), 256, 0, stream>>>(f1q, f1c, f2q, f2c, f3q, f3c, cw1, cb1, pm1);

  conv23_mfma<<<dim3(B, 3), 256, 0, stream>>>(pm1, w2p, cb2, w3p, cb3, feat);

  lin1_mfma<<<dim3(8, 4, 16), 256, 0, stream>>>(feat, wT, h1p);
  head_kernel<<<32, 256, 0, stream>>>(h1p, lb1, lw2, lb2, swt, sbs, (float*)d_out);
}

// Round 16
// 120.865 us; speedup vs baseline: 1.6169x; 1.0835x over previous
//
#include <hip/hip_runtime.h>
#include <hip/hip_bf16.h>

constexpr int B = 512, N = 64, E = 512, NE = B * E;

typedef __attribute__((ext_vector_type(8))) short bf8v;
typedef __attribute__((ext_vector_type(4))) float f32x4;
typedef unsigned short u16;

__device__ __forceinline__ u16 f2bf(float f) {
  unsigned u = __builtin_bit_cast(unsigned, f);
  u += 0x7FFFu + ((u >> 16) & 1u);
  return (u16)(u >> 16);
}

__device__ __forceinline__ int cmin(int a, int b) { return a < b ? a : b; }

// =================== fused 3-layer GCN via bf16 MFMA ===================
// Ab[d][s] (stride 72), Xb[n][k], Hb[c][s] chained in LDS; Wb aliases dead Af.
template <int DIN, int KP, int DOUT, bool STORE_NEXT>
__device__ __forceinline__ void gcn_layer_mfma(
    const u16* __restrict__ Ab, u16* __restrict__ Xb, u16* __restrict__ Hb,
    u16* __restrict__ Wb, const float* __restrict__ W,
    const float* __restrict__ bias, u16* __restrict__ fout, int g, int t) {
  // stage W[k][c] fp32 -> Wb[c][k] bf16 (zero-pad k in [DIN,KP))
  for (int i = t; i < DOUT * KP; i += 256) {
    int c = i / KP, k = i % KP;
    u16 v = 0;
    if (k < DIN) v = f2bf(W[k * DOUT + c]);
    Wb[c * 72 + k] = v;
  }
  __syncthreads();
  const int w4 = t >> 6, lane = t & 63;
  const int r16 = lane & 15, kg = lane >> 4;
  constexpr int CT = DOUT / 16;
  // mm1: H[n][c] = sum_k Xb[n][k] * Wb[c][k]; write Hb[c][n] (transposed)
#pragma unroll
  for (int ct = 0; ct < CT; ++ct) {
    f32x4 acc = {0.f, 0.f, 0.f, 0.f};
#pragma unroll
    for (int ks = 0; ks < KP; ks += 32) {
      bf8v a = *(const bf8v*)&Xb[(w4 * 16 + r16) * 72 + ks + kg * 8];
      bf8v bb = *(const bf8v*)&Wb[(ct * 16 + r16) * 72 + ks + kg * 8];
      acc = __builtin_amdgcn_mfma_f32_16x16x32_bf16(a, bb, acc, 0, 0, 0);
    }
    // lane holds col c=r16 (local), rows n = w4*16 + kg*4 + j
    ushort4 pk;
    pk.x = f2bf(acc[0]); pk.y = f2bf(acc[1]);
    pk.z = f2bf(acc[2]); pk.w = f2bf(acc[3]);
    *(ushort4*)&Hb[(ct * 16 + r16) * 72 + w4 * 16 + kg * 4] = pk;
  }
  __syncthreads();
  // mm2: out[d][c] = sum_s Ab[d][s] * Hb[c][s] + bias[c]
#pragma unroll
  for (int ct = 0; ct < CT; ++ct) {
    f32x4 acc = {0.f, 0.f, 0.f, 0.f};
#pragma unroll
    for (int ks = 0; ks < 64; ks += 32) {
      bf8v a = *(const bf8v*)&Ab[(w4 * 16 + r16) * 72 + ks + kg * 8];
      bf8v bb = *(const bf8v*)&Hb[(ct * 16 + r16) * 72 + ks + kg * 8];
      acc = __builtin_amdgcn_mfma_f32_16x16x32_bf16(a, bb, acc, 0, 0, 0);
    }
    const int c = ct * 16 + r16;
    const float bv = bias[c];
#pragma unroll
    for (int j = 0; j < 4; ++j) {
      float st = acc[j] + bv;
      const int d = w4 * 16 + kg * 4 + j;
      fout[(size_t)g * N * DOUT + (size_t)d * DOUT + c] = f2bf(st);
      if (STORE_NEXT) Xb[d * 72 + c] = f2bf(fmaxf(st, 0.f));
    }
  }
  __syncthreads();
}

__global__ __launch_bounds__(256) void gcn_fused(
    const float* __restrict__ xq, const float* __restrict__ xc,
    const float* __restrict__ W1, const float* __restrict__ b1,
    const float* __restrict__ W2, const float* __restrict__ b2,
    const float* __restrict__ W3, const float* __restrict__ b3,
    const int* __restrict__ eq, const int* __restrict__ ec,
    u16* __restrict__ f1q, u16* __restrict__ f1c,
    u16* __restrict__ f2q, u16* __restrict__ f2c,
    u16* __restrict__ f3q, u16* __restrict__ f3c) {
  __shared__ __align__(16) float Af[64 * 68];   // later aliased as Wb
  __shared__ __align__(16) u16 Ab[64 * 72];
  __shared__ __align__(16) u16 Xb[64 * 72];
  __shared__ __align__(16) u16 Hb[64 * 72];
  __shared__ float dl[N];
  __shared__ int cnt[N];
  u16* Wb = (u16*)Af;
  const int g = blockIdx.x, t = threadIdx.x;
  const float* x = blockIdx.y ? xc : xq;
  const int* edges = blockIdx.y ? ec : eq;
  u16* o1 = blockIdx.y ? f1c : f1q;
  u16* o2 = blockIdx.y ? f2c : f2q;
  u16* o3 = blockIdx.y ? f3c : f3q;
  // stage X -> bf16 [n][k], pad k 16..31 with 0
  for (int i = t; i < 64 * 32; i += 256) {
    int n = i >> 5, k = i & 31;
    u16 v = 0;
    if (k < 16) v = f2bf(x[(size_t)g * 1024 + n * 16 + k]);
    Xb[n * 72 + k] = v;
  }
  for (int i = t; i < 64 * 68; i += 256) Af[i] = 0.f;
  if (t < N) cnt[t] = 1;
  __syncthreads();
  const int* srcp = edges + (size_t)g * E;
  const int* dstp = edges + NE + (size_t)g * E;
  for (int j = t; j < E; j += 256) atomicAdd(&cnt[dstp[j] & 63], 1);
  __syncthreads();
  if (t < N) dl[t] = rsqrtf((float)cnt[t]);
  __syncthreads();
  for (int j = t; j < E; j += 256) {
    int s = srcp[j] & 63, d = dstp[j] & 63;
    atomicAdd(&Af[d * 68 + s], dl[s] * dl[d]);  // A[d][s]
  }
  if (t < N) atomicAdd(&Af[t * 68 + t], dl[t] * dl[t]);
  __syncthreads();
  for (int i = t; i < 4096; i += 256) {
    int d = i >> 6, s = i & 63;
    Ab[d * 72 + s] = f2bf(Af[d * 68 + s]);
  }
  __syncthreads();  // Af dead -> Wb usable
  gcn_layer_mfma<16, 32, 64, true>(Ab, Xb, Hb, Wb, W1, b1, o1, g, t);
  gcn_layer_mfma<64, 64, 32, true>(Ab, Xb, Hb, Wb, W2, b2, o2, g, t);
  gcn_layer_mfma<32, 32, 16, false>(Ab, Xb, Hb, Wb, W3, b3, o3, g, t);
}

// =================== fused sim (bf16 MFMA) + conv1 (fp32 VALU, oc-pairs) ===================
__global__ __launch_bounds__(256, 4) void simconv1(
    const u16* __restrict__ f1q, const u16* __restrict__ f1c,
    const u16* __restrict__ f2q, const u16* __restrict__ f2c,
    const u16* __restrict__ f3q, const u16* __restrict__ f3c,
    const float* __restrict__ w, const float* __restrict__ bias,
    u16* __restrict__ out) {
  constexpr int PS = 68, QS = 72;
  __shared__ __align__(16) u16 Qs[64 * QS];
  __shared__ __align__(16) u16 Cs[64 * QS];
  __shared__ __align__(16) float simp[68 * 68];
  __shared__ float wls[25 * 8];  // [tap][oc]
  __shared__ float bls[8];
  const int b = blockIdx.x, m = blockIdx.y, t = threadIdx.x;
  for (int i = t; i < 68 * 68; i += 256) simp[i] = 0.f;
  if (t < 200) {
    int oc = t / 25, tap = t % 25;
    wls[tap * 8 + oc] = w[m * 200 + t];
  }
  if (t < 8) bls[t] = bias[m * 8 + t];
  const u16* fq = (m == 0) ? f1q : (m == 1) ? f2q : f3q;
  const u16* fc = (m == 0) ? f1c : (m == 1) ? f2c : f3c;
  const int D = 64 >> m;
  const int SEG = D >> 3;
  for (int i = t; i < 64 * SEG; i += 256) {
    int n = i / SEG, s = i - n * SEG;
    *(uint4*)&Qs[n * QS + s * 8] = *(const uint4*)&fq[(size_t)b * 64 * D + n * D + s * 8];
    *(uint4*)&Cs[n * QS + s * 8] = *(const uint4*)&fc[(size_t)b * 64 * D + n * D + s * 8];
  }
  if (m == 2 && t < 128) {
    int n = t >> 1, s = t & 1;
    uint4 z = {0u, 0u, 0u, 0u};
    *(uint4*)&Qs[n * QS + 16 + s * 8] = z;
    *(uint4*)&Cs[n * QS + 16 + s * 8] = z;
  }
  __syncthreads();
  const int w4 = t >> 6, lane = t & 63;
  const int r16 = lane & 15, kg = lane >> 4;
  const int Kpad = (m == 0) ? 64 : 32;
#pragma unroll 1
  for (int ct = 0; ct < 4; ++ct) {
    f32x4 acc = {0.f, 0.f, 0.f, 0.f};
    for (int ks = 0; ks < Kpad; ks += 32) {
      bf8v a = *(const bf8v*)&Qs[(w4 * 16 + r16) * QS + ks + kg * 8];
      bf8v bb = *(const bf8v*)&Cs[(ct * 16 + r16) * QS + ks + kg * 8];
      acc = __builtin_amdgcn_mfma_f32_16x16x32_bf16(a, bb, acc, 0, 0, 0);
    }
#pragma unroll
    for (int j = 0; j < 4; ++j)
      simp[(w4 * 16 + kg * 4 + j + 2) * PS + ct * 16 + r16 + 2] = acc[j];
  }
  __syncthreads();
  const int gy = t >> 4, gx = t & 15;
  float pr[8][8];
#pragma unroll
  for (int yy = 0; yy < 8; ++yy) {
    float4 a = *(const float4*)&simp[(4 * gy + yy) * PS + 4 * gx];
    float4 bb = *(const float4*)&simp[(4 * gy + yy) * PS + 4 * gx + 4];
    pr[yy][0] = a.x; pr[yy][1] = a.y; pr[yy][2] = a.z; pr[yy][3] = a.w;
    pr[yy][4] = bb.x; pr[yy][5] = bb.y; pr[yy][6] = bb.z; pr[yy][7] = bb.w;
  }
  u16* op = out + (size_t)(b * 3 + m) * 8192;
#pragma unroll 1
  for (int p2 = 0; p2 < 4; ++p2) {
    float acc[2][16];
#pragma unroll
    for (int p = 0; p < 16; ++p) { acc[0][p] = 0.f; acc[1][p] = 0.f; }
#pragma unroll
    for (int ky = 0; ky < 5; ++ky)
#pragma unroll
      for (int kx = 0; kx < 5; ++kx) {
        float2 wv = *(const float2*)&wls[(ky * 5 + kx) * 8 + p2 * 2];
#pragma unroll
        for (int dy = 0; dy < 4; ++dy)
#pragma unroll
          for (int dx = 0; dx < 4; ++dx) {
            float rv = pr[ky + dy][kx + dx];
            acc[0][dy * 4 + dx] += rv * wv.x;
            acc[1][dy * 4 + dx] += rv * wv.y;
          }
      }
    float b0 = bls[p2 * 2], b1 = bls[p2 * 2 + 1];
#pragma unroll
    for (int ay = 0; ay < 2; ++ay)
#pragma unroll
      for (int ax = 0; ax < 2; ++ax) {
        float v0 = fmaxf(fmaxf(acc[0][(2 * ay) * 4 + 2 * ax], acc[0][(2 * ay) * 4 + 2 * ax + 1]),
                         fmaxf(acc[0][(2 * ay + 1) * 4 + 2 * ax], acc[0][(2 * ay + 1) * 4 + 2 * ax + 1]));
        float v1 = fmaxf(fmaxf(acc[1][(2 * ay) * 4 + 2 * ax], acc[1][(2 * ay) * 4 + 2 * ax + 1]),
                         fmaxf(acc[1][(2 * ay + 1) * 4 + 2 * ax], acc[1][(2 * ay + 1) * 4 + 2 * ax + 1]));
        v0 = fmaxf(v0 + b0, 0.f);
        v1 = fmaxf(v1 + b1, 0.f);
        unsigned pack = (unsigned)f2bf(v0) | ((unsigned)f2bf(v1) << 16);
        *(unsigned*)&op[(size_t)(((2 * gy + ay) * 32) + (2 * gx + ax)) * 8 + p2 * 2] = pack;
      }
  }
}

// =================== prep: wcvt (blocks 0..383) + wprep (blocks 384..579) ===================
__global__ __launch_bounds__(256) void prep_kernel(
    const float* __restrict__ lw1, const float* __restrict__ cw2,
    const float* __restrict__ cw3, u16* __restrict__ wT,
    u16* __restrict__ w2p, u16* __restrict__ w3p) {
  const int t = threadIdx.x;
  if (blockIdx.x < 384) {
    __shared__ float tile[64][65];
    const int k0 = (blockIdx.x % 96) * 64, c0 = (blockIdx.x / 96) * 64;
    for (int i = t; i < 4096; i += 256) {
      int r = i >> 6, c = i & 63;
      tile[r][c] = lw1[(size_t)(k0 + r) * 256 + c0 + c];
    }
    __syncthreads();
    for (int i = t; i < 4096; i += 256) {
      int c = i >> 6, k = i & 63;
      wT[(size_t)(c0 + c) * 6144 + k0 + k] = f2bf(tile[k][c]);
    }
    return;
  }
  int i = (blockIdx.x - 384) * 256 + t;
  if (i < 3 * 7 * 16 * 40) {
    int m = i / 4480, r = i % 4480;
    int k = r % 40, rest = r / 40, oc = rest & 15, st = rest >> 4;
    u16 v = 0;
    if (k < 32) {
      int sl = k >> 3, ci = k & 7, tap = st * 4 + sl;
      if (tap < 25) v = f2bf(cw2[((size_t)(m * 16 + oc) * 8 + ci) * 25 + tap]);
    }
    w2p[i] = v;
  }
  if (i < 3 * 26 * 16 * 40) {
    int m = i / 16640, r = i % 16640;
    int k = r % 40, rest = r / 40, oc16 = rest & 15, sthalf = rest >> 4;
    int half = sthalf & 1, st = sthalf >> 1;
    u16 v = 0;
    if (k < 32) {
      int sl = k >> 4, ci = k & 15, tap = st * 2 + sl;
      int oc = half * 16 + oc16;
      if (tap < 25) v = f2bf(cw3[((size_t)(m * 32 + oc) * 16 + ci) * 25 + tap]);
    }
    w3p[i] = v;
  }
}

// =================== conv2+conv3 fused (unchanged) ===================
__global__ __launch_bounds__(256) void conv23_mfma(
    const u16* __restrict__ in, const u16* __restrict__ w2p,
    const float* __restrict__ cb2, const u16* __restrict__ w3p,
    const float* __restrict__ cb3, u16* __restrict__ feat) {
  constexpr int PW2 = 36, PW3 = 20, BS = 40;
  __shared__ __align__(16) u16 uni[16640];
  __shared__ __align__(16) u16 p2s[PW3 * PW3 * 16];
  __shared__ float bls2[16];
  __shared__ float bls3[32];
  const int b = blockIdx.x, m = blockIdx.y, t = threadIdx.x;
  u16* ins2 = uni;
  u16* w2ls = uni + 10368;
  const size_t ibase = (size_t)(b * 3 + m) * 8192;
  for (int i = t; i < PW2 * PW2; i += 256) {
    int y = i / PW2, x = i % PW2;
    uint4 v = {0u, 0u, 0u, 0u};
    if (y >= 2 && y < 34 && x >= 2 && x < 34)
      v = *(const uint4*)&in[ibase + (size_t)((y - 2) * 32 + (x - 2)) * 8];
    *(uint4*)&ins2[i * 8] = v;
  }
  {
    const u16* wsrc = w2p + m * 4480;
    for (int i = t; i < 560; i += 256) *(uint4*)&w2ls[i * 8] = *(const uint4*)&wsrc[i * 8];
  }
  {
    uint4 z = {0u, 0u, 0u, 0u};
    for (int i = t; i < 800; i += 256) *(uint4*)&p2s[i * 8] = z;
  }
  if (t < 16) bls2[t] = cb2[m * 16 + t];
  if (t >= 32 && t < 64) bls3[t - 32] = cb3[m * 32 + (t - 32)];
  __syncthreads();
  const int wv = t >> 6, lane = t & 63;
  const int oc = lane & 15, g = lane >> 4;
  {
    const int xt = wv & 1, ypb = wv >> 1;
    const int x = xt * 16 + oc;
    __builtin_amdgcn_s_setprio(1);
#pragma unroll 1
    for (int grp = 0; grp < 2; ++grp) {
      f32x4 acc[4][2];
#pragma unroll
      for (int i = 0; i < 4; ++i) {
        acc[i][0] = (f32x4){0.f, 0.f, 0.f, 0.f};
        acc[i][1] = (f32x4){0.f, 0.f, 0.f, 0.f};
      }
#pragma unroll
      for (int st = 0; st < 7; ++st) {
        bf8v bvv = *(const bf8v*)&w2ls[(st * 16 + oc) * BS + g * 8];
        const int c0 = cmin(st * 4 + 0, 24), c1 = cmin(st * 4 + 1, 24);
        const int c2 = cmin(st * 4 + 2, 24), c3 = cmin(st * 4 + 3, 24);
        const int k0 = (c0 / 5) * PW2 + c0 % 5, k1 = (c1 / 5) * PW2 + c1 % 5;
        const int k2 = (c2 / 5) * PW2 + c2 % 5, k3 = (c3 / 5) * PW2 + c3 % 5;
        const int koff = (g == 0) ? k0 : (g == 1) ? k1 : (g == 2) ? k2 : k3;
#pragma unroll
        for (int i = 0; i < 4; ++i) {
          const int y0 = 2 * ypb + 4 * (grp * 4 + i);
          const int abase = (y0 * PW2 + x + koff) * 8;
          bf8v a0 = *(const bf8v*)&ins2[abase];
          acc[i][0] = __builtin_amdgcn_mfma_f32_16x16x32_bf16(a0, bvv, acc[i][0], 0, 0, 0);
          bf8v a1 = *(const bf8v*)&ins2[abase + PW2 * 8];
          acc[i][1] = __builtin_amdgcn_mfma_f32_16x16x32_bf16(a1, bvv, acc[i][1], 0, 0, 0);
        }
      }
      const float bb = bls2[oc];
#pragma unroll
      for (int i = 0; i < 4; ++i) {
        const int yp = ypb + 2 * (grp * 4 + i);
        const float v0 = fmaxf(fmaxf(fmaxf(acc[i][0][0], acc[i][0][1]),
                                     fmaxf(acc[i][1][0], acc[i][1][1])) + bb, 0.f);
        const float v1 = fmaxf(fmaxf(fmaxf(acc[i][0][2], acc[i][0][3]),
                                     fmaxf(acc[i][1][2], acc[i][1][3])) + bb, 0.f);
        const int px = xt * 8 + 2 * g;
        p2s[((yp + 2) * PW3 + (px + 2)) * 16 + oc] = f2bf(v0);
        p2s[((yp + 2) * PW3 + (px + 3)) * 16 + oc] = f2bf(v1);
      }
    }
    __builtin_amdgcn_s_setprio(0);
  }
  __syncthreads();
  {
    const u16* wsrc = w3p + m * 16640;
    for (int i = t; i < 2080; i += 256) *(uint4*)&uni[i * 8] = *(const uint4*)&wsrc[i * 8];
  }
  __syncthreads();
  {
    const int sl = g >> 1, ch = (g & 1) * 8;
    const int half = wv & 1, ypb = wv >> 1;
    u16* fb = feat + (size_t)b * 6144 + m * 2048;
    f32x4 acc[4][2];
#pragma unroll
    for (int i = 0; i < 4; ++i) {
      acc[i][0] = (f32x4){0.f, 0.f, 0.f, 0.f};
      acc[i][1] = (f32x4){0.f, 0.f, 0.f, 0.f};
    }
    __builtin_amdgcn_s_setprio(1);
#pragma unroll
    for (int st = 0; st < 13; ++st) {
      bf8v bvv = *(const bf8v*)&uni[(size_t)((st * 2 + half) * 16 + oc) * BS + g * 8];
      const int c0 = cmin(st * 2 + 0, 24), c1 = cmin(st * 2 + 1, 24);
      const int k0 = (c0 / 5) * PW3 + c0 % 5, k1 = (c1 / 5) * PW3 + c1 % 5;
      const int koff = sl ? k1 : k0;
#pragma unroll
      for (int i = 0; i < 4; ++i) {
        const int y0 = 2 * ypb + 4 * i;
        const int abase = (y0 * PW3 + oc + koff) * 16 + ch;
        bf8v a0 = *(const bf8v*)&p2s[abase];
        acc[i][0] = __builtin_amdgcn_mfma_f32_16x16x32_bf16(a0, bvv, acc[i][0], 0, 0, 0);
        bf8v a1 = *(const bf8v*)&p2s[abase + PW3 * 16];
        acc[i][1] = __builtin_amdgcn_mfma_f32_16x16x32_bf16(a1, bvv, acc[i][1], 0, 0, 0);
      }
    }
    __builtin_amdgcn_s_setprio(0);
    const int ocg = half * 16 + oc;
    const float bb = bls3[ocg];
#pragma unroll
    for (int i = 0; i < 4; ++i) {
      const int yp = ypb + 2 * i;
      const float v0 = fmaxf(fmaxf(fmaxf(acc[i][0][0], acc[i][0][1]),
                                   fmaxf(acc[i][1][0], acc[i][1][1])) + bb, 0.f);
      const float v1 = fmaxf(fmaxf(fmaxf(acc[i][0][2], acc[i][0][3]),
                                   fmaxf(acc[i][1][2], acc[i][1][3])) + bb, 0.f);
      unsigned pack = (unsigned)f2bf(v0) | ((unsigned)f2bf(v1) << 16);
      *(unsigned*)&fb[ocg * 64 + yp * 8 + 2 * g] = pack;
    }
  }
}

// =================== lin1: bf16 MFMA GEMM (unchanged) ===================
__global__ __launch_bounds__(256) void lin1_mfma(const u16* __restrict__ feat,
                                                 const u16* __restrict__ wT,
                                                 float* __restrict__ h1p) {
  constexpr int AS = 72;
  __shared__ __align__(16) u16 As[64 * AS];
  __shared__ __align__(16) u16 Bs[64 * AS];
  const int r0 = blockIdx.x * 64, c0 = blockIdx.y * 64, kb = blockIdx.z * 384;
  const int t = threadIdx.x;
  const int w = t >> 6, lane = t & 63;
  const int row16 = lane & 15, kg = lane >> 4;
  f32x4 acc[4] = {{0.f, 0.f, 0.f, 0.f}, {0.f, 0.f, 0.f, 0.f},
                  {0.f, 0.f, 0.f, 0.f}, {0.f, 0.f, 0.f, 0.f}};
  const int lr = t >> 2, lk = (t & 3) * 16;
#pragma unroll 1
  for (int st = 0; st < 6; ++st) {
    __syncthreads();
    const int ks = kb + st * 64;
    {
      const u16* srcA = feat + (size_t)(r0 + lr) * 6144 + ks + lk;
      uint4 a0 = *(const uint4*)srcA;
      uint4 a1 = *(const uint4*)(srcA + 8);
      *(uint4*)&As[lr * AS + lk] = a0;
      *(uint4*)&As[lr * AS + lk + 8] = a1;
      const u16* srcB = wT + (size_t)(c0 + lr) * 6144 + ks + lk;
      uint4 b0 = *(const uint4*)srcB;
      uint4 b1 = *(const uint4*)(srcB + 8);
      *(uint4*)&Bs[lr * AS + lk] = b0;
      *(uint4*)&Bs[lr * AS + lk + 8] = b1;
    }
    __syncthreads();
#pragma unroll
    for (int kk = 0; kk < 2; ++kk) {
      bf8v a = *(const bf8v*)&As[(w * 16 + row16) * AS + kk * 32 + kg * 8];
#pragma unroll
      for (int ct = 0; ct < 4; ++ct) {
        bf8v bb = *(const bf8v*)&Bs[(ct * 16 + row16) * AS + kk * 32 + kg * 8];
        acc[ct] = __builtin_amdgcn_mfma_f32_16x16x32_bf16(a, bb, acc[ct], 0, 0, 0);
      }
    }
  }
  float* out = h1p + (size_t)blockIdx.z * 131072;
#pragma unroll
  for (int ct = 0; ct < 4; ++ct)
#pragma unroll
    for (int j = 0; j < 4; ++j)
      out[(size_t)(r0 + w * 16 + kg * 4 + j) * 256 + c0 + ct * 16 + row16] = acc[ct][j];
}

// =================== head (unchanged) ===================
__global__ __launch_bounds__(256) void head_kernel(
    const float* __restrict__ h1p, const float* __restrict__ b1,
    const float* __restrict__ w2, const float* __restrict__ b2,
    const float* __restrict__ sw, const float* __restrict__ sb,
    float* __restrict__ out) {
  constexpr int HS = 260;
  __shared__ __align__(16) float h1s[16 * HS];
  __shared__ __align__(16) float w2s[256 * 16];
  const int r0 = blockIdx.x * 16, t = threadIdx.x;
  for (int i = t; i < 4096; i += 256) {
    int r = i >> 8, k = i & 255;
    float s = b1[k];
#pragma unroll
    for (int p = 0; p < 16; ++p) s += h1p[(size_t)p * 131072 + (size_t)(r0 + r) * 256 + k];
    h1s[r * HS + k] = s;
    w2s[i] = w2[i];
  }
  __syncthreads();
  const int j = t & 15, r = t >> 4;
  float acc = b2[j];
#pragma unroll 4
  for (int k4 = 0; k4 < 64; ++k4) {
    float4 hv = *(const float4*)&h1s[r * HS + 4 * k4];
    float h0 = fmaxf(hv.x, 0.f), h1v = fmaxf(hv.y, 0.f);
    float h2v = fmaxf(hv.z, 0.f), h3 = fmaxf(hv.w, 0.f);
    acc += h0 * w2s[(4 * k4 + 0) * 16 + j];
    acc += h1v * w2s[(4 * k4 + 1) * 16 + j];
    acc += h2v * w2s[(4 * k4 + 2) * 16 + j];
    acc += h3 * w2s[(4 * k4 + 3) * 16 + j];
  }
  float v = fmaxf(acc, 0.f) * sw[j];
#pragma unroll
  for (int off = 8; off; off >>= 1) v += __shfl_xor(v, off, 16);
  if (j == 0) out[r0 + r] = v + sb[0];
}

// =================== launcher ===================
extern "C" void kernel_launch(void* const* d_in, const int* in_sizes, int n_in,
                              void* d_out, int out_size, void* d_ws, size_t ws_size,
                              hipStream_t stream) {
  const float* x_q = (const float*)d_in[0];
  const float* x_c = (const float*)d_in[1];
  const int* edge_q = (const int*)d_in[2];
  const int* edge_c = (const int*)d_in[3];
  const float* gw1 = (const float*)d_in[4];
  const float* gb1 = (const float*)d_in[5];
  const float* gw2 = (const float*)d_in[6];
  const float* gb2 = (const float*)d_in[7];
  const float* gw3 = (const float*)d_in[8];
  const float* gb3 = (const float*)d_in[9];
  const float* cw1 = (const float*)d_in[10];
  const float* cb1 = (const float*)d_in[11];
  const float* cw2 = (const float*)d_in[12];
  const float* cb2 = (const float*)d_in[13];
  const float* cw3 = (const float*)d_in[14];
  const float* cb3 = (const float*)d_in[15];
  const float* lw1 = (const float*)d_in[16];
  const float* lb1 = (const float*)d_in[17];
  const float* lw2 = (const float*)d_in[18];
  const float* lb2 = (const float*)d_in[19];
  const float* swt = (const float*)d_in[20];
  const float* sbs = (const float*)d_in[21];
  float* ws = (float*)d_ws;

  const size_t o_f1q = 65536;
  const size_t o_f2q = o_f1q + 2097152;
  const size_t o_f3q = o_f2q + 1048576;
  const size_t o_f1c = o_f3q + 524288;
  const size_t o_f2c = o_f1c + 2097152;
  const size_t o_f3c = o_f2c + 1048576;
  const size_t o_sims = o_f3c + 524288;
  const size_t o_pm1 = o_sims + 6291456;
  const size_t o_pm2 = o_pm1 + 6291456;
  const size_t o_wT = o_pm2 + 3145728;
  const size_t o_w2p = o_wT + 786432;
  const size_t o_w3p = o_w2p + 8192;
  const size_t o_feat = o_sims;
  const size_t o_h1p = o_f1q;

  u16* f1q = (u16*)(ws + o_f1q); u16* f2q = (u16*)(ws + o_f2q); u16* f3q = (u16*)(ws + o_f3q);
  u16* f1c = (u16*)(ws + o_f1c); u16* f2c = (u16*)(ws + o_f2c); u16* f3c = (u16*)(ws + o_f3c);
  u16* pm1 = (u16*)(ws + o_pm1);
  u16* wT = (u16*)(ws + o_wT);
  u16* w2p = (u16*)(ws + o_w2p);
  u16* w3p = (u16*)(ws + o_w3p);
  u16* feat = (u16*)(ws + o_feat);
  float* h1p = ws + o_h1p;

  prep_kernel<<<580, 256, 0, stream>>>(lw1, cw2, cw3, wT, w2p, w3p);

  gcn_fused<<<dim3(B, 2), 256, 0, stream>>>(x_q, x_c, gw1, gb1, gw2, gb2, gw3, gb3,
                                            edge_q, edge_c, f1q, f1c, f2q, f2c, f3q, f3c);

  simconv1<<<dim3(B, 3), 256, 0, stream>>>(f1q, f1c, f2q, f2c, f3q, f3c, cw1, cb1, pm1);

  conv23_mfma<<<dim3(B, 3), 256, 0, stream>>>(pm1, w2p, cb2, w3p, cb3, feat);

  lin1_mfma<<<dim3(8, 4, 16), 256, 0, stream>>>(feat, wT, h1p);
  head_kernel<<<32, 256, 0, stream>>>(h1p, lb1, lw2, lb2, swt, sbs, (float*)d_out);
}